// Round 8
// baseline (1582.788 us; speedup 1.0000x reference)
//
#include <hip/hip_runtime.h>
#include <hip/hip_bf16.h>
#include <cstddef>

// ---------------------------------------------------------------------------
// UNet_config1 forward — MFMA implicit-GEMM, NHWC, fp16 storage / fp32 accum.
// R8 = R7 (coalesced swizzled weights, dbuf) + register diet: staging arrays
// packed into {lofl, g1} (fl/val bits in lofl; g2/fyfx recomputed per call)
// -> demand ~166 regs incl. 64 acc -> launch_bounds(256,3) = 3 blocks/CU.
// ---------------------------------------------------------------------------

typedef _Float16 h16;
typedef __attribute__((ext_vector_type(8))) _Float16 h16x8;
typedef __attribute__((ext_vector_type(4))) float f32x4;
union F8 { uint4 u; h16x8 h; };

__device__ __forceinline__ float h2f(unsigned short s) {
    union { h16 h; unsigned short s; } c; c.s = s; return (float)c.h;
}
__device__ __forceinline__ unsigned short f2h(float f) {
    union { h16 h; unsigned short s; } c; c.h = (h16)f; return c.s;
}
__device__ __forceinline__ unsigned pack2(float a, float b) {
    return (unsigned)f2h(a) | ((unsigned)f2h(b) << 16);
}
__device__ __forceinline__ void up8(const uint4& v, float* f) {
    f[0]=h2f(v.x&0xffff); f[1]=h2f(v.x>>16);
    f[2]=h2f(v.y&0xffff); f[3]=h2f(v.y>>16);
    f[4]=h2f(v.z&0xffff); f[5]=h2f(v.z>>16);
    f[6]=h2f(v.w&0xffff); f[7]=h2f(v.w>>16);
}

// ---- weight pack: fp32 [O][I][KH][KW] -> swizzled fp16 --------------------
// dst group index: (((ob*T + t)*nch + chunk)*(OB/16) + mt)*64 + lane, 8 h16
// each; A-frag load becomes base + lane*16B (fully coalesced).
__global__ void k_pack(const float* __restrict__ w, h16* __restrict__ pw,
                       int I, int T, int OB)
{
    int i8 = blockIdx.x * 64 + threadIdx.x;
    if (i8 >= (I >> 3)) return;
    int t = blockIdx.y, o = blockIdx.z;
    int ob = o / OB, om = o - ob * OB;
    int mt = om >> 4, m16 = om & 15;
    int chunk = i8 >> 2, quad = i8 & 3;
    int lane = quad * 16 + m16;
    int nch = I >> 5;
    size_t grp = ((((size_t)ob * T + t) * nch + chunk) * (OB >> 4) + mt) * 64 + lane;
    const float* src = w + ((size_t)o * I + i8 * 8) * T + t;
    h16* d = pw + grp * 8;
#pragma unroll
    for (int j = 0; j < 8; ++j) d[j] = (h16)src[(size_t)j * T];
}

// ---- implicit-GEMM conv: (16*MT) Cout x 256 px tile, 4 waves --------------
template<int KH, int KW, int PAD, bool UPS, int MT>
__global__ __launch_bounds__(256, 3) void k_conv_mfma(
    const h16* __restrict__ src1, int C1n, int H1, int W1,
    const h16* __restrict__ src2, int C2n,
    int Hin, int Win, int Ho, int Wo,
    const h16* __restrict__ PW, const float* __restrict__ bias,
    const float* __restrict__ pa, int aidx,
    h16* __restrict__ out, int Cout)
{
    constexpr int WINH = 8 + KH - 1, WINW = 32 + KW - 1;
    constexpr int NPIX = WINH * WINW;
    constexpr int NIT  = NPIX * 4;
    constexpr int MAXIT = (NIT + 255) / 256;
    constexpr int TAPS = KH * KW;
    __shared__ unsigned short lds[2][NPIX * 36];

    const int tid = threadIdx.x;
    const int lane = tid & 63, wv = tid >> 6;
    const int quad = lane >> 4, m16 = lane & 15;
    const int nCb = Cout / (16 * MT);
    const int b  = blockIdx.z / nCb, cb = blockIdx.z % nCb;
    const int x0 = blockIdx.x * 32, y0 = blockIdx.y * 8;
    const int Cin = C1n + C2n;
    const int nch = Cin >> 5;
    const int co_base = cb * (16 * MT);
    const int srcH = UPS ? Hin : H1;
    const int srcW = UPS ? Win : W1;

    const float ry = UPS ? (float)(H1 - 1) / (float)(Hin - 1) : 0.f;
    const float rx = UPS ? (float)(W1 - 1) / (float)(Win - 1) : 0.f;
    const int W1C = UPS ? W1 * C1n : 0;

    // ---- chunk-invariant staging precompute, packed to 2 arrays ----
    // lofl: bits0-15 = lds offset, bits16-17 = UPS edge flags, bit18 = valid;
    //       -1 = inactive. g1: src1 element offset, -1 = OOB.
    int lofl[MAXIT];
    int g1[MAXIT];
#pragma unroll
    for (int it = 0; it < MAXIT; ++it) {
        int i = tid + it * 256;
        if (i >= NIT) { lofl[it] = -1; g1[it] = -1; continue; }
        int p = i >> 2, q = i & 3;
        int wy = p / WINW, wx = p - wy * WINW;
        int yy = y0 - PAD + wy, xx = x0 - PAD + wx;
        int lof = p * 36 + q * 8;
        bool val = (unsigned)yy < (unsigned)srcH && (unsigned)xx < (unsigned)srcW;
        if (UPS) {
            int fl = 0;
            g1[it] = -1;
            if (val) {
                float ys = yy * ry, xs = xx * rx;
                int yl0 = (int)ys, xl0 = (int)xs;
                g1[it] = ((b * H1 + yl0) * W1 + xl0) * C1n + q * 8;
                fl = (yl0 < H1 - 1 ? 1 : 0) | (xl0 < W1 - 1 ? 2 : 0);
            }
            lofl[it] = lof | (fl << 16) | (val ? (1 << 18) : 0);
        } else {
            g1[it] = val ? ((b * H1 + yy) * W1 + xx) * C1n + q * 8 : -1;
            lofl[it] = lof;
        }
    }

    // ---- accumulators ----
    f32x4 acc[MT][4];
#pragma unroll
    for (int i = 0; i < MT; ++i)
#pragma unroll
        for (int j = 0; j < 4; ++j) acc[i][j] = (f32x4){0.f, 0.f, 0.f, 0.f};

    // ---- staging into a given LDS buffer ----
    auto stage = [&](int c0, unsigned short* buf) {
        if (UPS && c0 < C1n) {
#pragma unroll
            for (int it = 0; it < MAXIT; ++it) {
                int e = lofl[it];
                if (e < 0) continue;
                int lo = e & 0xFFFF;
                uint2 lo8 = {0u, 0u}, hi8 = {0u, 0u};
                int g = g1[it];
                if (g >= 0) {
                    // recompute interp fractions (chunk-invariant, cheap VALU)
                    int i = tid + it * 256;
                    int p = i >> 2;
                    int wy = p / WINW, wx = p - wy * WINW;
                    float ys = (y0 - PAD + wy) * ry;
                    float xs = (x0 - PAD + wx) * rx;
                    h16 fy = (h16)(ys - floorf(ys));
                    h16 fx = (h16)(xs - floorf(xs));
                    const h16* p00 = src1 + g + c0;
                    int oy = (e & (1 << 16)) ? W1C : 0;
                    int ox = (e & (2 << 16)) ? C1n : 0;
                    F8 v00, v01, v10, v11;
                    v00.u = *(const uint4*)(p00);
                    v01.u = *(const uint4*)(p00 + ox);
                    v10.u = *(const uint4*)(p00 + oy);
                    v11.u = *(const uint4*)(p00 + oy + ox);
                    h16x8 r0 = v00.h + (v10.h - v00.h) * fy;
                    h16x8 r1 = v01.h + (v11.h - v01.h) * fy;
                    F8 rr; rr.h = r0 + (r1 - r0) * fx;
                    lo8 = make_uint2(rr.u.x, rr.u.y);
                    hi8 = make_uint2(rr.u.z, rr.u.w);
                }
                *(uint2*)&buf[lo] = lo8;
                *(uint2*)&buf[lo + 4] = hi8;
            }
        } else if (UPS) {
            int cs = c0 - C1n;
#pragma unroll
            for (int it = 0; it < MAXIT; ++it) {
                int e = lofl[it];
                if (e < 0) continue;
                int lo = e & 0xFFFF;
                uint4 v = {0u, 0u, 0u, 0u};
                if (e & (1 << 18)) {
                    // recompute skip-source offset (chunk-invariant)
                    int i = tid + it * 256;
                    int q = i & 3, p = i >> 2;
                    int wy = p / WINW, wx = p - wy * WINW;
                    int yy = y0 - PAD + wy, xx = x0 - PAD + wx;
                    v = *(const uint4*)(src2 + ((b * Hin + yy) * Win + xx) * C2n + q * 8 + cs);
                }
                *(uint2*)&buf[lo] = make_uint2(v.x, v.y);
                *(uint2*)&buf[lo + 4] = make_uint2(v.z, v.w);
            }
        } else {
#pragma unroll
            for (int it = 0; it < MAXIT; ++it) {
                int e = lofl[it];
                if (e < 0) continue;
                uint4 v = {0u, 0u, 0u, 0u};
                int g = g1[it];
                if (g >= 0) v = *(const uint4*)(src1 + g + c0);
                *(uint2*)&buf[e] = make_uint2(v.x, v.y);
                *(uint2*)&buf[e + 4] = make_uint2(v.z, v.w);
            }
        }
    };

    // ---- MFMA sweep; A-frags via coalesced swizzled loads ----
    const uint4* PW4 = (const uint4*)PW;
    auto sweep = [&](int ci, const unsigned short* buf) {
        size_t abase = (((size_t)cb * TAPS) * nch + ci) * (MT * 64) + lane;
        const size_t astep = (size_t)nch * (MT * 64);
#pragma unroll
        for (int ky = 0; ky < KH; ++ky) {
#pragma unroll
            for (int kx = 0; kx < KW; ++kx) {
                const int tap = ky * KW + kx;
                F8 a[MT];
#pragma unroll
                for (int mt = 0; mt < MT; ++mt)
                    a[mt].u = PW4[abase + (size_t)tap * astep + mt * 64];
#pragma unroll
                for (int nt = 0; nt < 4; ++nt) {
                    int rowl = (wv << 1) + (nt >> 1);
                    int col  = ((nt & 1) << 4) + m16;
                    int li = ((rowl + ky) * WINW + col + kx) * 36 + quad * 8;
                    F8 bf;
                    ((uint2*)&bf)[0] = *(const uint2*)&buf[li];
                    ((uint2*)&bf)[1] = *(const uint2*)&buf[li + 4];
#pragma unroll
                    for (int mt = 0; mt < MT; ++mt)
                        acc[mt][nt] = __builtin_amdgcn_mfma_f32_16x16x32_f16(
                            a[mt].h, bf.h, acc[mt][nt], 0, 0, 0);
                }
            }
        }
    };

    // ---- double-buffered K-loop: one barrier per chunk ----
    stage(0, lds[0]);
    __syncthreads();
    for (int ci = 0; ci < nch; ++ci) {
        int p = ci & 1;
        if (ci + 1 < nch) stage((ci + 1) << 5, lds[p ^ 1]);
        sweep(ci, lds[p]);
        __syncthreads();
    }

    // ---- epilogue: bias + PReLU, NHWC store ----
    const float alpha = pa[aidx];
#pragma unroll
    for (int mt = 0; mt < MT; ++mt) {
        int co = co_base + mt * 16 + quad * 4;
        float4 bi = *(const float4*)(bias + co);
#pragma unroll
        for (int nt = 0; nt < 4; ++nt) {
            int y = y0 + (wv << 1) + (nt >> 1);
            int x = x0 + ((nt & 1) << 4) + m16;
            float v0 = acc[mt][nt][0] + bi.x;
            float v1 = acc[mt][nt][1] + bi.y;
            float v2 = acc[mt][nt][2] + bi.z;
            float v3 = acc[mt][nt][3] + bi.w;
            v0 = v0 >= 0.f ? v0 : alpha * v0;
            v1 = v1 >= 0.f ? v1 : alpha * v1;
            v2 = v2 >= 0.f ? v2 : alpha * v2;
            v3 = v3 >= 0.f ? v3 : alpha * v3;
            uint2 r; r.x = pack2(v0, v1); r.y = pack2(v2, v3);
            *(uint2*)(out + ((size_t)((b * Ho + y) * Wo + x)) * Cout + co) = r;
        }
    }
}

// ---- dynamic per-sample conv 8x8 pad3 + PReLU[0], NHWC out ----------------
__global__ __launch_bounds__(256) void k_dynconv(
    const float* __restrict__ x,   // [8,256,256] fp32
    const float* __restrict__ w,   // [8,32,8,8] fp32
    const float* __restrict__ pa,
    h16* __restrict__ out)         // [8,255,255,32] NHWC
{
    __shared__ float wl[2048];     // [tap][co]
    int b = blockIdx.y;
    for (int j = threadIdx.x; j < 2048; j += 256) {
        int t = j >> 5, co = j & 31;
        wl[j] = w[((size_t)(b * 32 + co)) * 64 + t];
    }
    __syncthreads();
    int idx = blockIdx.x * 256 + threadIdx.x;
    if (idx >= 65025) return;
    int py = idx / 255, px = idx - py * 255;
    float acc[32];
#pragma unroll
    for (int c = 0; c < 32; ++c) acc[c] = 0.f;
    const float* xp = x + (size_t)b * 65536;
#pragma unroll
    for (int ky = 0; ky < 8; ++ky) {
        int iy = py + ky - 3;
        if ((unsigned)iy >= 256u) continue;
        const float* row = xp + iy * 256;
#pragma unroll
        for (int kx = 0; kx < 8; ++kx) {
            int ix = px + kx - 3;
            if ((unsigned)ix >= 256u) continue;
            float v = row[ix];
            const float4* wr = (const float4*)&wl[(ky * 8 + kx) * 32];
#pragma unroll
            for (int cg = 0; cg < 8; ++cg) {
                float4 wv = wr[cg];
                acc[cg*4+0] += v * wv.x; acc[cg*4+1] += v * wv.y;
                acc[cg*4+2] += v * wv.z; acc[cg*4+3] += v * wv.w;
            }
        }
    }
    float a = pa[0];
    h16* op = out + ((size_t)(b * 65025 + idx)) * 32;
#pragma unroll
    for (int cg = 0; cg < 4; ++cg) {
        float v[8];
#pragma unroll
        for (int k = 0; k < 8; ++k) {
            float t = acc[cg * 8 + k];
            v[k] = t >= 0.f ? t : a * t;
        }
        uint4 r;
        r.x = pack2(v[0], v[1]); r.y = pack2(v[2], v[3]);
        r.z = pack2(v[4], v[5]); r.w = pack2(v[6], v[7]);
        *(uint4*)(op + cg * 8) = r;
    }
}

// ---- maxpool 2x2, NHWC, vector 8ch ----------------------------------------
__global__ __launch_bounds__(256) void k_pool(
    const h16* __restrict__ in, h16* __restrict__ out,
    int Hin, int Win, int C, int lc8, int lwo, int count)
{
    int idx = blockIdx.x * 256 + threadIdx.x;
    if (idx >= count) return;
    int b = blockIdx.y;
    int c8 = idx & ((1 << lc8) - 1);
    int t  = idx >> lc8;
    int ox = t & ((1 << lwo) - 1);
    int oy = t >> lwo;
    const h16* p = in + ((size_t)((b * Hin + oy * 2) * Win + ox * 2)) * C + c8 * 8;
    uint4 v00 = *(const uint4*)p;
    uint4 v01 = *(const uint4*)(p + C);
    uint4 v10 = *(const uint4*)(p + (size_t)Win * C);
    uint4 v11 = *(const uint4*)(p + (size_t)Win * C + C);
    float a[8], bb[8], c[8], d[8];
    up8(v00, a); up8(v01, bb); up8(v10, c); up8(v11, d);
    uint4 r;
    float m[8];
#pragma unroll
    for (int k = 0; k < 8; ++k) m[k] = fmaxf(fmaxf(a[k], bb[k]), fmaxf(c[k], d[k]));
    r.x = pack2(m[0], m[1]); r.y = pack2(m[2], m[3]);
    r.z = pack2(m[4], m[5]); r.w = pack2(m[6], m[7]);
    int Wo = 1 << lwo;
    *(uint4*)(out + ((size_t)((b * (Hin >> 1) + oy) * Wo + ox)) * C + c8 * 8) = r;
}

// ---- BatchNorm (training stats), NHWC -------------------------------------
__global__ __launch_bounds__(256) void k_bnstats(
    const h16* __restrict__ x, int C, int N, float* __restrict__ sums)
{
    __shared__ float ls[1024];
    for (int j = threadIdx.x; j < 2 * C; j += 256) ls[j] = 0.f;
    __syncthreads();
    int start = blockIdx.x * 256 + threadIdx.x;
    int stride = gridDim.x * 256;
    int c = start & (C - 1);
    float s = 0.f, q = 0.f;
    for (int i = start; i < N; i += stride) {
        float v = h2f(((const unsigned short*)x)[i]);
        s += v; q += v * v;
    }
    atomicAdd(&ls[c], s);
    atomicAdd(&ls[C + c], q);
    __syncthreads();
    for (int j = threadIdx.x; j < 2 * C; j += 256) atomicAdd(&sums[j], ls[j]);
}

__global__ void k_bnfin(
    const float* __restrict__ sums, const float* __restrict__ g,
    const float* __restrict__ bta, int C, float invN, float* __restrict__ sc)
{
    int c = threadIdx.x;
    if (c >= C) return;
    float mean = sums[c] * invN;
    float var  = sums[C + c] * invN - mean * mean;
    float s    = g[c] / sqrtf(var + 1e-5f);
    sc[c]      = s;
    sc[C + c]  = bta[c] - mean * s;
}

__global__ __launch_bounds__(256) void k_bnapply(
    h16* __restrict__ x, int C, int N8, const float* __restrict__ sc)
{
    __shared__ float ls[1024];
    for (int j = threadIdx.x; j < 2 * C; j += 256) ls[j] = sc[j];
    __syncthreads();
    int idx = blockIdx.x * 256 + threadIdx.x;
    if (idx >= N8) return;
    int cb = (idx << 3) & (C - 1);
    h16* p = x + (size_t)idx * 8;
    uint4 v = *(const uint4*)p;
    float f[8];
    up8(v, f);
    uint4 r;
    float o[8];
#pragma unroll
    for (int k = 0; k < 8; ++k) o[k] = f[k] * ls[cb + k] + ls[C + cb + k];
    r.x = pack2(o[0], o[1]); r.y = pack2(o[2], o[3]);
    r.z = pack2(o[4], o[5]); r.w = pack2(o[6], o[7]);
    *(uint4*)p = r;
}

// ---- final 1x1 conv 32->1, fp32 out ---------------------------------------
__global__ __launch_bounds__(256) void k_final(
    const h16* __restrict__ in, const float* __restrict__ w,
    const float* __restrict__ bias, float* __restrict__ out)
{
    int idx = blockIdx.x * 256 + threadIdx.x;
    if (idx >= 524288) return;
    const h16* p = in + (size_t)idx * 32;
    float acc = bias[0];
#pragma unroll
    for (int cg = 0; cg < 4; ++cg) {
        uint4 v = *(const uint4*)(p + cg * 8);
        float f[8];
        up8(v, f);
#pragma unroll
        for (int k = 0; k < 8; ++k) acc += f[k] * w[cg * 8 + k];
    }
    out[idx] = acc;
}

extern "C" void kernel_launch(void* const* d_in, const int* in_sizes, int n_in,
                              void* d_out, int out_size, void* d_ws, size_t ws_size,
                              hipStream_t stream)
{
    const float* x      = (const float*)d_in[0];
    const float* w      = (const float*)d_in[1];
    const float* c1_w   = (const float*)d_in[2];
    const float* c1_b   = (const float*)d_in[3];
    const float* d2_w1  = (const float*)d_in[4];
    const float* d2_b1  = (const float*)d_in[5];
    const float* d2_w2  = (const float*)d_in[6];
    const float* d2_b2  = (const float*)d_in[7];
    const float* d3_w1  = (const float*)d_in[8];
    const float* d3_b1  = (const float*)d_in[9];
    const float* d3_w2  = (const float*)d_in[10];
    const float* d3_b2  = (const float*)d_in[11];
    const float* d4_w1  = (const float*)d_in[12];
    const float* d4_b1  = (const float*)d_in[13];
    const float* d4_w2  = (const float*)d_in[14];
    const float* d4_b2  = (const float*)d_in[15];
    const float* u3_w1  = (const float*)d_in[16];
    const float* u3_b1  = (const float*)d_in[17];
    const float* u3_w2  = (const float*)d_in[18];
    const float* u3_b2  = (const float*)d_in[19];
    const float* u2_w1  = (const float*)d_in[20];
    const float* u2_b1  = (const float*)d_in[21];
    const float* u2_w2  = (const float*)d_in[22];
    const float* u2_b2  = (const float*)d_in[23];
    const float* u1_w1  = (const float*)d_in[24];
    const float* u1_b1  = (const float*)d_in[25];
    const float* u1_w2  = (const float*)d_in[26];
    const float* u1_b2  = (const float*)d_in[27];
    const float* last_w = (const float*)d_in[28];
    const float* last_b = (const float*)d_in[29];
    const float* bn1_g  = (const float*)d_in[30];
    const float* bn1_b  = (const float*)d_in[31];
    const float* bn2_g  = (const float*)d_in[32];
    const float* bn2_b  = (const float*)d_in[33];
    const float* bn3_g  = (const float*)d_in[34];
    const float* bn3_b  = (const float*)d_in[35];
    const float* bn4_g  = (const float*)d_in[36];
    const float* bn4_b  = (const float*)d_in[37];
    const float* pa     = (const float*)d_in[38];
    float* out = (float*)d_out;

    // ---- fp16 arena (identical to R3-R7, proven: 166.3 MB) ----
    h16* A0 = (h16*)d_ws;
    h16* C1 = A0;                   // c1 skip  [8,256,256,32]
    h16* C2 = A0 + 16777216;        // c2 skip  [8,128,128,128]
    h16* C3 = A0 + 33554432;        // c3 skip  [8,64,64,256]
    h16* A  = A0 + 41943040;        // t0/t1/t2/t3/u3mid/u2mid/u1mid
    h16* B  = A0 + 58720256;        // p1/p2/p3/h4/u3out/u2out/u1out
    h16* PWb= A0 + 75497472;        // packed fp16 weights (swizzled)
    float* SUMS = (float*)(A0 + 83126272);
    float* SC   = SUMS + 1024;
    size_t need = (size_t)83126272 * 2 + 8192;
    if (ws_size < need) return;

    h16* pw_c1   = PWb;
    h16* pw_d2w1 = PWb + 16384;
    h16* pw_d2w2 = PWb + 53248;
    h16* pw_d3w1 = PWb + 200704;
    h16* pw_d3w2 = PWb + 495616;
    h16* pw_d4w1 = PWb + 1085440;
    h16* pw_d4w2 = PWb + 2265088;
    h16* pw_u3w1 = PWb + 4624384;
    h16* pw_u3w2 = PWb + 6393856;
    h16* pw_u2w1 = PWb + 6983680;
    h16* pw_u2w2 = PWb + 7426048;
    h16* pw_u1w1 = PWb + 7573504;
    h16* pw_u1w2 = PWb + 7619584;

    dim3 blk(256);

    // pack with swizzle; OB = 16*MT of the consuming conv kernel
    auto pack = [&](const float* src, h16* dst, int I, int T, int O, int OB) {
        k_pack<<<dim3(((I >> 3) + 63) / 64, T, O), 64, 0, stream>>>(src, dst, I, T, OB);
    };
    pack(c1_w,  pw_c1,   32, 16, 32, 32);
    pack(d2_w1, pw_d2w1, 32,  9, 128, 64);
    pack(d2_w2, pw_d2w2, 128, 9, 128, 64);
    pack(d3_w1, pw_d3w1, 128, 9, 256, 64);
    pack(d3_w2, pw_d3w2, 256, 9, 256, 64);
    pack(d4_w1, pw_d4w1, 256, 9, 512, 64);
    pack(d4_w2, pw_d4w2, 512, 9, 512, 64);
    pack(u3_w1, pw_u3w1, 768, 9, 256, 64);
    pack(u3_w2, pw_u3w2, 256, 9, 256, 64);
    pack(u2_w1, pw_u2w1, 384, 9, 128, 64);
    pack(u2_w2, pw_u2w2, 128, 9, 128, 64);
    pack(u1_w1, pw_u1w1, 160, 9, 32, 32);
    pack(u1_w2, pw_u1w2, 32,  9, 32, 32);

    auto bn = [&](h16* buf, int C, int N, const float* g, const float* bb) {
        hipMemsetAsync(SUMS, 0, 2 * C * sizeof(float), stream);
        k_bnstats<<<dim3(1024), blk, 0, stream>>>(buf, C, N, SUMS);
        k_bnfin<<<dim3(1), dim3(512), 0, stream>>>(SUMS, g, bb, C, (float)C / (float)N, SC);
        k_bnapply<<<dim3(N / 8 / 256), blk, 0, stream>>>(buf, C, N / 8, SC);
    };

    // ---- encoder ----
    k_dynconv<<<dim3(255, 8), blk, 0, stream>>>(x, w, pa, A);   // t0 -> A
    k_conv_mfma<4,4,2,false,2><<<dim3(8, 32, 8), blk, 0, stream>>>(
        A, 32, 255, 255, nullptr, 0, 255, 255, 256, 256,
        pw_c1, c1_b, pa, 1, C1, 32);
    bn(C1, 32, 16777216, bn1_g, bn1_b);
    k_pool<<<dim3(256, 8), blk, 0, stream>>>(C1, B, 256, 256, 32, 2, 7, 65536);   // p1

    k_conv_mfma<3,3,1,false,4><<<dim3(4, 16, 16), blk, 0, stream>>>(
        B, 32, 128, 128, nullptr, 0, 128, 128, 128, 128,
        pw_d2w1, d2_b1, pa, 2, A, 128);                                            // t1
    k_conv_mfma<3,3,1,false,4><<<dim3(4, 16, 16), blk, 0, stream>>>(
        A, 128, 128, 128, nullptr, 0, 128, 128, 128, 128,
        pw_d2w2, d2_b2, pa, 3, C2, 128);
    bn(C2, 128, 16777216, bn2_g, bn2_b);
    k_pool<<<dim3(256, 8), blk, 0, stream>>>(C2, B, 128, 128, 128, 4, 6, 65536);  // p2

    k_conv_mfma<3,3,1,false,4><<<dim3(2, 8, 32), blk, 0, stream>>>(
        B, 128, 64, 64, nullptr, 0, 64, 64, 64, 64,
        pw_d3w1, d3_b1, pa, 4, A, 256);                                            // t2
    k_conv_mfma<3,3,1,false,4><<<dim3(2, 8, 32), blk, 0, stream>>>(
        A, 256, 64, 64, nullptr, 0, 64, 64, 64, 64,
        pw_d3w2, d3_b2, pa, 5, C3, 256);
    bn(C3, 256, 8388608, bn3_g, bn3_b);
    k_pool<<<dim3(128, 8), blk, 0, stream>>>(C3, B, 64, 64, 256, 5, 5, 32768);    // p3

    k_conv_mfma<3,3,1,false,4><<<dim3(1, 4, 64), blk, 0, stream>>>(
        B, 256, 32, 32, nullptr, 0, 32, 32, 32, 32,
        pw_d4w1, d4_b1, pa, 6, A, 512);                                            // t3
    k_conv_mfma<3,3,1,false,4><<<dim3(1, 4, 64), blk, 0, stream>>>(
        A, 512, 32, 32, nullptr, 0, 32, 32, 32, 32,
        pw_d4w2, d4_b2, pa, 7, B, 512);                                            // h4
    bn(B, 512, 4194304, bn4_g, bn4_b);

    // ---- decoder (bilinear up2 fused into staging) ----
    k_conv_mfma<3,3,1,true,4><<<dim3(2, 8, 32), blk, 0, stream>>>(
        B, 512, 32, 32, C3, 256, 64, 64, 64, 64,
        pw_u3w1, u3_b1, pa, 8, A, 256);                                            // u3mid
    k_conv_mfma<3,3,1,false,4><<<dim3(2, 8, 32), blk, 0, stream>>>(
        A, 256, 64, 64, nullptr, 0, 64, 64, 64, 64,
        pw_u3w2, u3_b2, pa, 9, B, 256);                                            // u3out

    k_conv_mfma<3,3,1,true,4><<<dim3(4, 16, 16), blk, 0, stream>>>(
        B, 256, 64, 64, C2, 128, 128, 128, 128, 128,
        pw_u2w1, u2_b1, pa, 10, A, 128);                                           // u2mid
    k_conv_mfma<3,3,1,false,4><<<dim3(4, 16, 16), blk, 0, stream>>>(
        A, 128, 128, 128, nullptr, 0, 128, 128, 128, 128,
        pw_u2w2, u2_b2, pa, 11, B, 128);                                           // u2out

    k_conv_mfma<3,3,1,true,2><<<dim3(8, 32, 8), blk, 0, stream>>>(
        B, 128, 128, 128, C1, 32, 256, 256, 256, 256,
        pw_u1w1, u1_b1, pa, 12, A, 32);                                            // u1mid
    k_conv_mfma<3,3,1,false,2><<<dim3(8, 32, 8), blk, 0, stream>>>(
        A, 32, 256, 256, nullptr, 0, 256, 256, 256, 256,
        pw_u1w2, u1_b2, pa, 13, B, 32);                                            // u1out

    k_final<<<dim3(2048), blk, 0, stream>>>(B, last_w, last_b, out);
}

// Round 9
// 1220.643 us; speedup vs baseline: 1.2967x; 1.2967x over previous
//
#include <hip/hip_runtime.h>
#include <hip/hip_bf16.h>
#include <cstddef>

// ---------------------------------------------------------------------------
// UNet_config1 forward — MFMA implicit-GEMM, NHWC, fp16 storage / fp32 accum.
// R9 = R7 (coalesced swizzled weights, dbuf, launch_bounds(256,2), persistent
// staging arrays) + row-cached sweep: kx-outer / window-row-inner so each
// distinct B-fragment is read from LDS once (24 loads vs 36) and feeds 8
// consecutive MFMAs. NOTE: (256,3) spills with 64-AGPR acc — R6/R8 both
// proved it; do not reattempt.
// ---------------------------------------------------------------------------

typedef _Float16 h16;
typedef __attribute__((ext_vector_type(8))) _Float16 h16x8;
typedef __attribute__((ext_vector_type(4))) float f32x4;
union F8 { uint4 u; h16x8 h; };
union UH { unsigned u; h16 h[2]; };

__device__ __forceinline__ float h2f(unsigned short s) {
    union { h16 h; unsigned short s; } c; c.s = s; return (float)c.h;
}
__device__ __forceinline__ unsigned short f2h(float f) {
    union { h16 h; unsigned short s; } c; c.h = (h16)f; return c.s;
}
__device__ __forceinline__ unsigned pack2(float a, float b) {
    return (unsigned)f2h(a) | ((unsigned)f2h(b) << 16);
}
__device__ __forceinline__ void up8(const uint4& v, float* f) {
    f[0]=h2f(v.x&0xffff); f[1]=h2f(v.x>>16);
    f[2]=h2f(v.y&0xffff); f[3]=h2f(v.y>>16);
    f[4]=h2f(v.z&0xffff); f[5]=h2f(v.z>>16);
    f[6]=h2f(v.w&0xffff); f[7]=h2f(v.w>>16);
}

// ---- weight pack: fp32 [O][I][KH][KW] -> swizzled fp16 --------------------
// dst group: (((ob*T + t)*nch + chunk)*(OB/16) + mt)*64 + lane, 8 h16 each.
// A-frag load = base + lane*16B, fully coalesced.
__global__ void k_pack(const float* __restrict__ w, h16* __restrict__ pw,
                       int I, int T, int OB)
{
    int i8 = blockIdx.x * 64 + threadIdx.x;
    if (i8 >= (I >> 3)) return;
    int t = blockIdx.y, o = blockIdx.z;
    int ob = o / OB, om = o - ob * OB;
    int mt = om >> 4, m16 = om & 15;
    int chunk = i8 >> 2, quad = i8 & 3;
    int lane = quad * 16 + m16;
    int nch = I >> 5;
    size_t grp = ((((size_t)ob * T + t) * nch + chunk) * (OB >> 4) + mt) * 64 + lane;
    const float* src = w + ((size_t)o * I + i8 * 8) * T + t;
    h16* d = pw + grp * 8;
#pragma unroll
    for (int j = 0; j < 8; ++j) d[j] = (h16)src[(size_t)j * T];
}

// ---- implicit-GEMM conv: (16*MT) Cout x 256 px tile, 4 waves --------------
template<int KH, int KW, int PAD, bool UPS, int MT>
__global__ __launch_bounds__(256, 2) void k_conv_mfma(
    const h16* __restrict__ src1, int C1n, int H1, int W1,
    const h16* __restrict__ src2, int C2n,
    int Hin, int Win, int Ho, int Wo,
    const h16* __restrict__ PW, const float* __restrict__ bias,
    const float* __restrict__ pa, int aidx,
    h16* __restrict__ out, int Cout)
{
    constexpr int WINH = 8 + KH - 1, WINW = 32 + KW - 1;
    constexpr int NPIX = WINH * WINW;
    constexpr int NIT  = NPIX * 4;
    constexpr int MAXIT = (NIT + 255) / 256;
    constexpr int TAPS = KH * KW;
    __shared__ unsigned short lds[2][NPIX * 36];

    const int tid = threadIdx.x;
    const int lane = tid & 63, wv = tid >> 6;
    const int quad = lane >> 4, m16 = lane & 15;
    const int nCb = Cout / (16 * MT);
    const int b  = blockIdx.z / nCb, cb = blockIdx.z % nCb;
    const int x0 = blockIdx.x * 32, y0 = blockIdx.y * 8;
    const int Cin = C1n + C2n;
    const int nch = Cin >> 5;
    const int co_base = cb * (16 * MT);
    const int srcH = UPS ? Hin : H1;
    const int srcW = UPS ? Win : W1;

    // ---- chunk-invariant staging precompute (registers) ----
    int lof[MAXIT];
    int g1[MAXIT];
    int fl[MAXIT];
    unsigned fyfx[MAXIT];
    int g2[MAXIT];

    const float ry = UPS ? (float)(H1 - 1) / (float)(Hin - 1) : 0.f;
    const float rx = UPS ? (float)(W1 - 1) / (float)(Win - 1) : 0.f;
    const int W1C = UPS ? W1 * C1n : 0;

#pragma unroll
    for (int it = 0; it < MAXIT; ++it) {
        int i = tid + it * 256;
        if (i >= NIT) { lof[it] = -1; g1[it] = -1; g2[it] = -1; fl[it] = 0; fyfx[it] = 0; continue; }
        int p = i >> 2, q = i & 3;
        int wy = p / WINW, wx = p - wy * WINW;
        int yy = y0 - PAD + wy, xx = x0 - PAD + wx;
        lof[it] = p * 36 + q * 8;
        bool val = (unsigned)yy < (unsigned)srcH && (unsigned)xx < (unsigned)srcW;
        if (UPS) {
            fl[it] = 0; fyfx[it] = 0; g1[it] = -1; g2[it] = -1;
            if (val) {
                float ys = yy * ry, xs = xx * rx;
                int yl0 = (int)ys, xl0 = (int)xs;
                float fy = ys - (float)yl0, fx = xs - (float)xl0;
                g1[it] = ((b * H1 + yl0) * W1 + xl0) * C1n + q * 8;
                fl[it] = (yl0 < H1 - 1 ? 1 : 0) | (xl0 < W1 - 1 ? 2 : 0);
                fyfx[it] = pack2(fy, fx);
                g2[it] = ((b * Hin + yy) * Win + xx) * C2n + q * 8;
            }
        } else {
            fl[it] = 0; fyfx[it] = 0; g2[it] = -1;
            g1[it] = val ? ((b * H1 + yy) * W1 + xx) * C1n + q * 8 : -1;
        }
    }

    // ---- accumulators ----
    f32x4 acc[MT][4];
#pragma unroll
    for (int i = 0; i < MT; ++i)
#pragma unroll
        for (int j = 0; j < 4; ++j) acc[i][j] = (f32x4){0.f, 0.f, 0.f, 0.f};

    // ---- staging into a given LDS buffer ----
    auto stage = [&](int c0, unsigned short* buf) {
        if (UPS && c0 < C1n) {
#pragma unroll
            for (int it = 0; it < MAXIT; ++it) {
                int lo = lof[it];
                if (lo < 0) continue;
                uint2 lo8 = {0u, 0u}, hi8 = {0u, 0u};
                int g = g1[it];
                if (g >= 0) {
                    const h16* p00 = src1 + g + c0;
                    int oy = (fl[it] & 1) ? W1C : 0;
                    int ox = (fl[it] & 2) ? C1n : 0;
                    F8 v00, v01, v10, v11;
                    v00.u = *(const uint4*)(p00);
                    v01.u = *(const uint4*)(p00 + ox);
                    v10.u = *(const uint4*)(p00 + oy);
                    v11.u = *(const uint4*)(p00 + oy + ox);
                    UH t; t.u = fyfx[it];
                    h16 fy = t.h[0], fx = t.h[1];
                    h16x8 r0 = v00.h + (v10.h - v00.h) * fy;
                    h16x8 r1 = v01.h + (v11.h - v01.h) * fy;
                    F8 rr; rr.h = r0 + (r1 - r0) * fx;
                    lo8 = make_uint2(rr.u.x, rr.u.y);
                    hi8 = make_uint2(rr.u.z, rr.u.w);
                }
                *(uint2*)&buf[lo] = lo8;
                *(uint2*)&buf[lo + 4] = hi8;
            }
        } else if (UPS) {
            int cs = c0 - C1n;
#pragma unroll
            for (int it = 0; it < MAXIT; ++it) {
                int lo = lof[it];
                if (lo < 0) continue;
                uint4 v = {0u, 0u, 0u, 0u};
                int g = g2[it];
                if (g >= 0) v = *(const uint4*)(src2 + g + cs);
                *(uint2*)&buf[lo] = make_uint2(v.x, v.y);
                *(uint2*)&buf[lo + 4] = make_uint2(v.z, v.w);
            }
        } else {
#pragma unroll
            for (int it = 0; it < MAXIT; ++it) {
                int lo = lof[it];
                if (lo < 0) continue;
                uint4 v = {0u, 0u, 0u, 0u};
                int g = g1[it];
                if (g >= 0) v = *(const uint4*)(src1 + g + c0);
                *(uint2*)&buf[lo] = make_uint2(v.x, v.y);
                *(uint2*)&buf[lo + 4] = make_uint2(v.z, v.w);
            }
        }
    };

    // ---- row-cached MFMA sweep: each distinct B-fragment read once -------
    // window row wr = ntr + ky (ntr = nt>>1); loop kx outer with all-ky A
    // frags resident, then wr/cg inner: one B load feeds up to 2*MT MFMAs.
    const uint4* PW4 = (const uint4*)PW;
    auto sweep = [&](int ci, const unsigned short* buf) {
        size_t abase = (((size_t)cb * TAPS) * nch + ci) * (MT * 64) + lane;
        const size_t astep = (size_t)nch * (MT * 64);
#pragma unroll
        for (int kx = 0; kx < KW; ++kx) {
            F8 a[KH][MT];
#pragma unroll
            for (int ky = 0; ky < KH; ++ky)
#pragma unroll
                for (int mt = 0; mt < MT; ++mt)
                    a[ky][mt].u = PW4[abase + (size_t)(ky * KW + kx) * astep + mt * 64];
#pragma unroll
            for (int wr = 0; wr < 2 + KH - 1; ++wr) {
#pragma unroll
                for (int cg = 0; cg < 2; ++cg) {
                    int row = (wv << 1) + wr;
                    int col = (cg << 4) + m16;
                    int li = (row * WINW + col + kx) * 36 + quad * 8;
                    F8 bf;
                    ((uint2*)&bf)[0] = *(const uint2*)&buf[li];
                    ((uint2*)&bf)[1] = *(const uint2*)&buf[li + 4];
#pragma unroll
                    for (int ky = 0; ky < KH; ++ky) {
                        int ntr = wr - ky;
                        if (ntr < 0 || ntr > 1) continue;
                        int nt = (ntr << 1) + cg;
#pragma unroll
                        for (int mt = 0; mt < MT; ++mt)
                            acc[mt][nt] = __builtin_amdgcn_mfma_f32_16x16x32_f16(
                                a[ky][mt].h, bf.h, acc[mt][nt], 0, 0, 0);
                    }
                }
            }
        }
    };

    // ---- double-buffered K-loop: one barrier per chunk ----
    stage(0, lds[0]);
    __syncthreads();
    for (int ci = 0; ci < nch; ++ci) {
        int p = ci & 1;
        if (ci + 1 < nch) stage((ci + 1) << 5, lds[p ^ 1]);
        sweep(ci, lds[p]);
        __syncthreads();
    }

    // ---- epilogue: bias + PReLU, NHWC store ----
    const float alpha = pa[aidx];
#pragma unroll
    for (int mt = 0; mt < MT; ++mt) {
        int co = co_base + mt * 16 + quad * 4;
        float4 bi = *(const float4*)(bias + co);
#pragma unroll
        for (int nt = 0; nt < 4; ++nt) {
            int y = y0 + (wv << 1) + (nt >> 1);
            int x = x0 + ((nt & 1) << 4) + m16;
            float v0 = acc[mt][nt][0] + bi.x;
            float v1 = acc[mt][nt][1] + bi.y;
            float v2 = acc[mt][nt][2] + bi.z;
            float v3 = acc[mt][nt][3] + bi.w;
            v0 = v0 >= 0.f ? v0 : alpha * v0;
            v1 = v1 >= 0.f ? v1 : alpha * v1;
            v2 = v2 >= 0.f ? v2 : alpha * v2;
            v3 = v3 >= 0.f ? v3 : alpha * v3;
            uint2 r; r.x = pack2(v0, v1); r.y = pack2(v2, v3);
            *(uint2*)(out + ((size_t)((b * Ho + y) * Wo + x)) * Cout + co) = r;
        }
    }
}

// ---- dynamic per-sample conv 8x8 pad3 + PReLU[0], NHWC out ----------------
__global__ __launch_bounds__(256) void k_dynconv(
    const float* __restrict__ x,   // [8,256,256] fp32
    const float* __restrict__ w,   // [8,32,8,8] fp32
    const float* __restrict__ pa,
    h16* __restrict__ out)         // [8,255,255,32] NHWC
{
    __shared__ float wl[2048];     // [tap][co]
    int b = blockIdx.y;
    for (int j = threadIdx.x; j < 2048; j += 256) {
        int t = j >> 5, co = j & 31;
        wl[j] = w[((size_t)(b * 32 + co)) * 64 + t];
    }
    __syncthreads();
    int idx = blockIdx.x * 256 + threadIdx.x;
    if (idx >= 65025) return;
    int py = idx / 255, px = idx - py * 255;
    float acc[32];
#pragma unroll
    for (int c = 0; c < 32; ++c) acc[c] = 0.f;
    const float* xp = x + (size_t)b * 65536;
#pragma unroll
    for (int ky = 0; ky < 8; ++ky) {
        int iy = py + ky - 3;
        if ((unsigned)iy >= 256u) continue;
        const float* row = xp + iy * 256;
#pragma unroll
        for (int kx = 0; kx < 8; ++kx) {
            int ix = px + kx - 3;
            if ((unsigned)ix >= 256u) continue;
            float v = row[ix];
            const float4* wr = (const float4*)&wl[(ky * 8 + kx) * 32];
#pragma unroll
            for (int cg = 0; cg < 8; ++cg) {
                float4 wv = wr[cg];
                acc[cg*4+0] += v * wv.x; acc[cg*4+1] += v * wv.y;
                acc[cg*4+2] += v * wv.z; acc[cg*4+3] += v * wv.w;
            }
        }
    }
    float a = pa[0];
    h16* op = out + ((size_t)(b * 65025 + idx)) * 32;
#pragma unroll
    for (int cg = 0; cg < 4; ++cg) {
        float v[8];
#pragma unroll
        for (int k = 0; k < 8; ++k) {
            float t = acc[cg * 8 + k];
            v[k] = t >= 0.f ? t : a * t;
        }
        uint4 r;
        r.x = pack2(v[0], v[1]); r.y = pack2(v[2], v[3]);
        r.z = pack2(v[4], v[5]); r.w = pack2(v[6], v[7]);
        *(uint4*)(op + cg * 8) = r;
    }
}

// ---- maxpool 2x2, NHWC, vector 8ch ----------------------------------------
__global__ __launch_bounds__(256) void k_pool(
    const h16* __restrict__ in, h16* __restrict__ out,
    int Hin, int Win, int C, int lc8, int lwo, int count)
{
    int idx = blockIdx.x * 256 + threadIdx.x;
    if (idx >= count) return;
    int b = blockIdx.y;
    int c8 = idx & ((1 << lc8) - 1);
    int t  = idx >> lc8;
    int ox = t & ((1 << lwo) - 1);
    int oy = t >> lwo;
    const h16* p = in + ((size_t)((b * Hin + oy * 2) * Win + ox * 2)) * C + c8 * 8;
    uint4 v00 = *(const uint4*)p;
    uint4 v01 = *(const uint4*)(p + C);
    uint4 v10 = *(const uint4*)(p + (size_t)Win * C);
    uint4 v11 = *(const uint4*)(p + (size_t)Win * C + C);
    float a[8], bb[8], c[8], d[8];
    up8(v00, a); up8(v01, bb); up8(v10, c); up8(v11, d);
    uint4 r;
    float m[8];
#pragma unroll
    for (int k = 0; k < 8; ++k) m[k] = fmaxf(fmaxf(a[k], bb[k]), fmaxf(c[k], d[k]));
    r.x = pack2(m[0], m[1]); r.y = pack2(m[2], m[3]);
    r.z = pack2(m[4], m[5]); r.w = pack2(m[6], m[7]);
    int Wo = 1 << lwo;
    *(uint4*)(out + ((size_t)((b * (Hin >> 1) + oy) * Wo + ox)) * C + c8 * 8) = r;
}

// ---- BatchNorm (training stats), NHWC -------------------------------------
__global__ __launch_bounds__(256) void k_bnstats(
    const h16* __restrict__ x, int C, int N, float* __restrict__ sums)
{
    __shared__ float ls[1024];
    for (int j = threadIdx.x; j < 2 * C; j += 256) ls[j] = 0.f;
    __syncthreads();
    int start = blockIdx.x * 256 + threadIdx.x;
    int stride = gridDim.x * 256;
    int c = start & (C - 1);
    float s = 0.f, q = 0.f;
    for (int i = start; i < N; i += stride) {
        float v = h2f(((const unsigned short*)x)[i]);
        s += v; q += v * v;
    }
    atomicAdd(&ls[c], s);
    atomicAdd(&ls[C + c], q);
    __syncthreads();
    for (int j = threadIdx.x; j < 2 * C; j += 256) atomicAdd(&sums[j], ls[j]);
}

__global__ void k_bnfin(
    const float* __restrict__ sums, const float* __restrict__ g,
    const float* __restrict__ bta, int C, float invN, float* __restrict__ sc)
{
    int c = threadIdx.x;
    if (c >= C) return;
    float mean = sums[c] * invN;
    float var  = sums[C + c] * invN - mean * mean;
    float s    = g[c] / sqrtf(var + 1e-5f);
    sc[c]      = s;
    sc[C + c]  = bta[c] - mean * s;
}

__global__ __launch_bounds__(256) void k_bnapply(
    h16* __restrict__ x, int C, int N8, const float* __restrict__ sc)
{
    __shared__ float ls[1024];
    for (int j = threadIdx.x; j < 2 * C; j += 256) ls[j] = sc[j];
    __syncthreads();
    int idx = blockIdx.x * 256 + threadIdx.x;
    if (idx >= N8) return;
    int cb = (idx << 3) & (C - 1);
    h16* p = x + (size_t)idx * 8;
    uint4 v = *(const uint4*)p;
    float f[8];
    up8(v, f);
    uint4 r;
    float o[8];
#pragma unroll
    for (int k = 0; k < 8; ++k) o[k] = f[k] * ls[cb + k] + ls[C + cb + k];
    r.x = pack2(o[0], o[1]); r.y = pack2(o[2], o[3]);
    r.z = pack2(o[4], o[5]); r.w = pack2(o[6], o[7]);
    *(uint4*)p = r;
}

// ---- final 1x1 conv 32->1, fp32 out ---------------------------------------
__global__ __launch_bounds__(256) void k_final(
    const h16* __restrict__ in, const float* __restrict__ w,
    const float* __restrict__ bias, float* __restrict__ out)
{
    int idx = blockIdx.x * 256 + threadIdx.x;
    if (idx >= 524288) return;
    const h16* p = in + (size_t)idx * 32;
    float acc = bias[0];
#pragma unroll
    for (int cg = 0; cg < 4; ++cg) {
        uint4 v = *(const uint4*)(p + cg * 8);
        float f[8];
        up8(v, f);
#pragma unroll
        for (int k = 0; k < 8; ++k) acc += f[k] * w[cg * 8 + k];
    }
    out[idx] = acc;
}

extern "C" void kernel_launch(void* const* d_in, const int* in_sizes, int n_in,
                              void* d_out, int out_size, void* d_ws, size_t ws_size,
                              hipStream_t stream)
{
    const float* x      = (const float*)d_in[0];
    const float* w      = (const float*)d_in[1];
    const float* c1_w   = (const float*)d_in[2];
    const float* c1_b   = (const float*)d_in[3];
    const float* d2_w1  = (const float*)d_in[4];
    const float* d2_b1  = (const float*)d_in[5];
    const float* d2_w2  = (const float*)d_in[6];
    const float* d2_b2  = (const float*)d_in[7];
    const float* d3_w1  = (const float*)d_in[8];
    const float* d3_b1  = (const float*)d_in[9];
    const float* d3_w2  = (const float*)d_in[10];
    const float* d3_b2  = (const float*)d_in[11];
    const float* d4_w1  = (const float*)d_in[12];
    const float* d4_b1  = (const float*)d_in[13];
    const float* d4_w2  = (const float*)d_in[14];
    const float* d4_b2  = (const float*)d_in[15];
    const float* u3_w1  = (const float*)d_in[16];
    const float* u3_b1  = (const float*)d_in[17];
    const float* u3_w2  = (const float*)d_in[18];
    const float* u3_b2  = (const float*)d_in[19];
    const float* u2_w1  = (const float*)d_in[20];
    const float* u2_b1  = (const float*)d_in[21];
    const float* u2_w2  = (const float*)d_in[22];
    const float* u2_b2  = (const float*)d_in[23];
    const float* u1_w1  = (const float*)d_in[24];
    const float* u1_b1  = (const float*)d_in[25];
    const float* u1_w2  = (const float*)d_in[26];
    const float* u1_b2  = (const float*)d_in[27];
    const float* last_w = (const float*)d_in[28];
    const float* last_b = (const float*)d_in[29];
    const float* bn1_g  = (const float*)d_in[30];
    const float* bn1_b  = (const float*)d_in[31];
    const float* bn2_g  = (const float*)d_in[32];
    const float* bn2_b  = (const float*)d_in[33];
    const float* bn3_g  = (const float*)d_in[34];
    const float* bn3_b  = (const float*)d_in[35];
    const float* bn4_g  = (const float*)d_in[36];
    const float* bn4_b  = (const float*)d_in[37];
    const float* pa     = (const float*)d_in[38];
    float* out = (float*)d_out;

    // ---- fp16 arena (identical to R3-R8, proven: 166.3 MB) ----
    h16* A0 = (h16*)d_ws;
    h16* C1 = A0;                   // c1 skip  [8,256,256,32]
    h16* C2 = A0 + 16777216;        // c2 skip  [8,128,128,128]
    h16* C3 = A0 + 33554432;        // c3 skip  [8,64,64,256]
    h16* A  = A0 + 41943040;        // t0/t1/t2/t3/u3mid/u2mid/u1mid
    h16* B  = A0 + 58720256;        // p1/p2/p3/h4/u3out/u2out/u1out
    h16* PWb= A0 + 75497472;        // packed fp16 weights (swizzled)
    float* SUMS = (float*)(A0 + 83126272);
    float* SC   = SUMS + 1024;
    size_t need = (size_t)83126272 * 2 + 8192;
    if (ws_size < need) return;

    h16* pw_c1   = PWb;
    h16* pw_d2w1 = PWb + 16384;
    h16* pw_d2w2 = PWb + 53248;
    h16* pw_d3w1 = PWb + 200704;
    h16* pw_d3w2 = PWb + 495616;
    h16* pw_d4w1 = PWb + 1085440;
    h16* pw_d4w2 = PWb + 2265088;
    h16* pw_u3w1 = PWb + 4624384;
    h16* pw_u3w2 = PWb + 6393856;
    h16* pw_u2w1 = PWb + 6983680;
    h16* pw_u2w2 = PWb + 7426048;
    h16* pw_u1w1 = PWb + 7573504;
    h16* pw_u1w2 = PWb + 7619584;

    dim3 blk(256);

    // pack with swizzle; OB = 16*MT of the consuming conv kernel
    auto pack = [&](const float* src, h16* dst, int I, int T, int O, int OB) {
        k_pack<<<dim3(((I >> 3) + 63) / 64, T, O), 64, 0, stream>>>(src, dst, I, T, OB);
    };
    pack(c1_w,  pw_c1,   32, 16, 32, 32);
    pack(d2_w1, pw_d2w1, 32,  9, 128, 64);
    pack(d2_w2, pw_d2w2, 128, 9, 128, 64);
    pack(d3_w1, pw_d3w1, 128, 9, 256, 64);
    pack(d3_w2, pw_d3w2, 256, 9, 256, 64);
    pack(d4_w1, pw_d4w1, 256, 9, 512, 64);
    pack(d4_w2, pw_d4w2, 512, 9, 512, 64);
    pack(u3_w1, pw_u3w1, 768, 9, 256, 64);
    pack(u3_w2, pw_u3w2, 256, 9, 256, 64);
    pack(u2_w1, pw_u2w1, 384, 9, 128, 64);
    pack(u2_w2, pw_u2w2, 128, 9, 128, 64);
    pack(u1_w1, pw_u1w1, 160, 9, 32, 32);
    pack(u1_w2, pw_u1w2, 32,  9, 32, 32);

    auto bn = [&](h16* buf, int C, int N, const float* g, const float* bb) {
        hipMemsetAsync(SUMS, 0, 2 * C * sizeof(float), stream);
        k_bnstats<<<dim3(1024), blk, 0, stream>>>(buf, C, N, SUMS);
        k_bnfin<<<dim3(1), dim3(512), 0, stream>>>(SUMS, g, bb, C, (float)C / (float)N, SC);
        k_bnapply<<<dim3(N / 8 / 256), blk, 0, stream>>>(buf, C, N / 8, SC);
    };

    // ---- encoder ----
    k_dynconv<<<dim3(255, 8), blk, 0, stream>>>(x, w, pa, A);   // t0 -> A
    k_conv_mfma<4,4,2,false,2><<<dim3(8, 32, 8), blk, 0, stream>>>(
        A, 32, 255, 255, nullptr, 0, 255, 255, 256, 256,
        pw_c1, c1_b, pa, 1, C1, 32);
    bn(C1, 32, 16777216, bn1_g, bn1_b);
    k_pool<<<dim3(256, 8), blk, 0, stream>>>(C1, B, 256, 256, 32, 2, 7, 65536);   // p1

    k_conv_mfma<3,3,1,false,4><<<dim3(4, 16, 16), blk, 0, stream>>>(
        B, 32, 128, 128, nullptr, 0, 128, 128, 128, 128,
        pw_d2w1, d2_b1, pa, 2, A, 128);                                            // t1
    k_conv_mfma<3,3,1,false,4><<<dim3(4, 16, 16), blk, 0, stream>>>(
        A, 128, 128, 128, nullptr, 0, 128, 128, 128, 128,
        pw_d2w2, d2_b2, pa, 3, C2, 128);
    bn(C2, 128, 16777216, bn2_g, bn2_b);
    k_pool<<<dim3(256, 8), blk, 0, stream>>>(C2, B, 128, 128, 128, 4, 6, 65536);  // p2

    k_conv_mfma<3,3,1,false,4><<<dim3(2, 8, 32), blk, 0, stream>>>(
        B, 128, 64, 64, nullptr, 0, 64, 64, 64, 64,
        pw_d3w1, d3_b1, pa, 4, A, 256);                                            // t2
    k_conv_mfma<3,3,1,false,4><<<dim3(2, 8, 32), blk, 0, stream>>>(
        A, 256, 64, 64, nullptr, 0, 64, 64, 64, 64,
        pw_d3w2, d3_b2, pa, 5, C3, 256);
    bn(C3, 256, 8388608, bn3_g, bn3_b);
    k_pool<<<dim3(128, 8), blk, 0, stream>>>(C3, B, 64, 64, 256, 5, 5, 32768);    // p3

    k_conv_mfma<3,3,1,false,4><<<dim3(1, 4, 64), blk, 0, stream>>>(
        B, 256, 32, 32, nullptr, 0, 32, 32, 32, 32,
        pw_d4w1, d4_b1, pa, 6, A, 512);                                            // t3
    k_conv_mfma<3,3,1,false,4><<<dim3(1, 4, 64), blk, 0, stream>>>(
        A, 512, 32, 32, nullptr, 0, 32, 32, 32, 32,
        pw_d4w2, d4_b2, pa, 7, B, 512);                                            // h4
    bn(B, 512, 4194304, bn4_g, bn4_b);

    // ---- decoder (bilinear up2 fused into staging) ----
    k_conv_mfma<3,3,1,true,4><<<dim3(2, 8, 32), blk, 0, stream>>>(
        B, 512, 32, 32, C3, 256, 64, 64, 64, 64,
        pw_u3w1, u3_b1, pa, 8, A, 256);                                            // u3mid
    k_conv_mfma<3,3,1,false,4><<<dim3(2, 8, 32), blk, 0, stream>>>(
        A, 256, 64, 64, nullptr, 0, 64, 64, 64, 64,
        pw_u3w2, u3_b2, pa, 9, B, 256);                                            // u3out

    k_conv_mfma<3,3,1,true,4><<<dim3(4, 16, 16), blk, 0, stream>>>(
        B, 256, 64, 64, C2, 128, 128, 128, 128, 128,
        pw_u2w1, u2_b1, pa, 10, A, 128);                                           // u2mid
    k_conv_mfma<3,3,1,false,4><<<dim3(4, 16, 16), blk, 0, stream>>>(
        A, 128, 128, 128, nullptr, 0, 128, 128, 128, 128,
        pw_u2w2, u2_b2, pa, 11, B, 128);                                           // u2out

    k_conv_mfma<3,3,1,true,2><<<dim3(8, 32, 8), blk, 0, stream>>>(
        B, 128, 128, 128, C1, 32, 256, 256, 256, 256,
        pw_u1w1, u1_b1, pa, 12, A, 32);                                            // u1mid
    k_conv_mfma<3,3,1,false,2><<<dim3(8, 32, 8), blk, 0, stream>>>(
        A, 32, 256, 256, nullptr, 0, 256, 256, 256, 256,
        pw_u1w2, u1_b2, pa, 13, B, 32);                                            // u1out

    k_final<<<dim3(2048), blk, 0, stream>>>(B, last_w, last_b, out);
}

// Round 10
// 1216.073 us; speedup vs baseline: 1.3016x; 1.0038x over previous
//
#include <hip/hip_runtime.h>
#include <hip/hip_bf16.h>
#include <cstddef>

// ---------------------------------------------------------------------------
// UNet_config1 forward — MFMA implicit-GEMM, NHWC, fp16 storage / fp32 accum.
// R10 = R9 + (1) A-fragment kx-group double-buffering (hide L2 latency of
// weight loads behind MFMA: vmcnt(N) partial waits instead of full drains),
// (2) d4 layers at MT=2 (grid 256->512 blocks, 1->2 blocks/CU).
// NOTE: (256,3) spills with 64-AGPR acc — R6/R8 proved it; do not reattempt.
// ---------------------------------------------------------------------------

typedef _Float16 h16;
typedef __attribute__((ext_vector_type(8))) _Float16 h16x8;
typedef __attribute__((ext_vector_type(4))) float f32x4;
union F8 { uint4 u; h16x8 h; };
union UH { unsigned u; h16 h[2]; };

__device__ __forceinline__ float h2f(unsigned short s) {
    union { h16 h; unsigned short s; } c; c.s = s; return (float)c.h;
}
__device__ __forceinline__ unsigned short f2h(float f) {
    union { h16 h; unsigned short s; } c; c.h = (h16)f; return c.s;
}
__device__ __forceinline__ unsigned pack2(float a, float b) {
    return (unsigned)f2h(a) | ((unsigned)f2h(b) << 16);
}
__device__ __forceinline__ void up8(const uint4& v, float* f) {
    f[0]=h2f(v.x&0xffff); f[1]=h2f(v.x>>16);
    f[2]=h2f(v.y&0xffff); f[3]=h2f(v.y>>16);
    f[4]=h2f(v.z&0xffff); f[5]=h2f(v.z>>16);
    f[6]=h2f(v.w&0xffff); f[7]=h2f(v.w>>16);
}

// ---- weight pack: fp32 [O][I][KH][KW] -> swizzled fp16 --------------------
// dst group: (((ob*T + t)*nch + chunk)*(OB/16) + mt)*64 + lane, 8 h16 each.
// A-frag load = base + lane*16B, fully coalesced.
__global__ void k_pack(const float* __restrict__ w, h16* __restrict__ pw,
                       int I, int T, int OB)
{
    int i8 = blockIdx.x * 64 + threadIdx.x;
    if (i8 >= (I >> 3)) return;
    int t = blockIdx.y, o = blockIdx.z;
    int ob = o / OB, om = o - ob * OB;
    int mt = om >> 4, m16 = om & 15;
    int chunk = i8 >> 2, quad = i8 & 3;
    int lane = quad * 16 + m16;
    int nch = I >> 5;
    size_t grp = ((((size_t)ob * T + t) * nch + chunk) * (OB >> 4) + mt) * 64 + lane;
    const float* src = w + ((size_t)o * I + i8 * 8) * T + t;
    h16* d = pw + grp * 8;
#pragma unroll
    for (int j = 0; j < 8; ++j) d[j] = (h16)src[(size_t)j * T];
}

// ---- implicit-GEMM conv: (16*MT) Cout x 256 px tile, 4 waves --------------
template<int KH, int KW, int PAD, bool UPS, int MT>
__global__ __launch_bounds__(256, 2) void k_conv_mfma(
    const h16* __restrict__ src1, int C1n, int H1, int W1,
    const h16* __restrict__ src2, int C2n,
    int Hin, int Win, int Ho, int Wo,
    const h16* __restrict__ PW, const float* __restrict__ bias,
    const float* __restrict__ pa, int aidx,
    h16* __restrict__ out, int Cout)
{
    constexpr int WINH = 8 + KH - 1, WINW = 32 + KW - 1;
    constexpr int NPIX = WINH * WINW;
    constexpr int NIT  = NPIX * 4;
    constexpr int MAXIT = (NIT + 255) / 256;
    constexpr int TAPS = KH * KW;
    __shared__ unsigned short lds[2][NPIX * 36];

    const int tid = threadIdx.x;
    const int lane = tid & 63, wv = tid >> 6;
    const int quad = lane >> 4, m16 = lane & 15;
    const int nCb = Cout / (16 * MT);
    const int b  = blockIdx.z / nCb, cb = blockIdx.z % nCb;
    const int x0 = blockIdx.x * 32, y0 = blockIdx.y * 8;
    const int Cin = C1n + C2n;
    const int nch = Cin >> 5;
    const int co_base = cb * (16 * MT);
    const int srcH = UPS ? Hin : H1;
    const int srcW = UPS ? Win : W1;

    // ---- chunk-invariant staging precompute (registers) ----
    int lof[MAXIT];
    int g1[MAXIT];
    int fl[MAXIT];
    unsigned fyfx[MAXIT];
    int g2[MAXIT];

    const float ry = UPS ? (float)(H1 - 1) / (float)(Hin - 1) : 0.f;
    const float rx = UPS ? (float)(W1 - 1) / (float)(Win - 1) : 0.f;
    const int W1C = UPS ? W1 * C1n : 0;

#pragma unroll
    for (int it = 0; it < MAXIT; ++it) {
        int i = tid + it * 256;
        if (i >= NIT) { lof[it] = -1; g1[it] = -1; g2[it] = -1; fl[it] = 0; fyfx[it] = 0; continue; }
        int p = i >> 2, q = i & 3;
        int wy = p / WINW, wx = p - wy * WINW;
        int yy = y0 - PAD + wy, xx = x0 - PAD + wx;
        lof[it] = p * 36 + q * 8;
        bool val = (unsigned)yy < (unsigned)srcH && (unsigned)xx < (unsigned)srcW;
        if (UPS) {
            fl[it] = 0; fyfx[it] = 0; g1[it] = -1; g2[it] = -1;
            if (val) {
                float ys = yy * ry, xs = xx * rx;
                int yl0 = (int)ys, xl0 = (int)xs;
                float fy = ys - (float)yl0, fx = xs - (float)xl0;
                g1[it] = ((b * H1 + yl0) * W1 + xl0) * C1n + q * 8;
                fl[it] = (yl0 < H1 - 1 ? 1 : 0) | (xl0 < W1 - 1 ? 2 : 0);
                fyfx[it] = pack2(fy, fx);
                g2[it] = ((b * Hin + yy) * Win + xx) * C2n + q * 8;
            }
        } else {
            fl[it] = 0; fyfx[it] = 0; g2[it] = -1;
            g1[it] = val ? ((b * H1 + yy) * W1 + xx) * C1n + q * 8 : -1;
        }
    }

    // ---- accumulators ----
    f32x4 acc[MT][4];
#pragma unroll
    for (int i = 0; i < MT; ++i)
#pragma unroll
        for (int j = 0; j < 4; ++j) acc[i][j] = (f32x4){0.f, 0.f, 0.f, 0.f};

    // ---- staging into a given LDS buffer ----
    auto stage = [&](int c0, unsigned short* buf) {
        if (UPS && c0 < C1n) {
#pragma unroll
            for (int it = 0; it < MAXIT; ++it) {
                int lo = lof[it];
                if (lo < 0) continue;
                uint2 lo8 = {0u, 0u}, hi8 = {0u, 0u};
                int g = g1[it];
                if (g >= 0) {
                    const h16* p00 = src1 + g + c0;
                    int oy = (fl[it] & 1) ? W1C : 0;
                    int ox = (fl[it] & 2) ? C1n : 0;
                    F8 v00, v01, v10, v11;
                    v00.u = *(const uint4*)(p00);
                    v01.u = *(const uint4*)(p00 + ox);
                    v10.u = *(const uint4*)(p00 + oy);
                    v11.u = *(const uint4*)(p00 + oy + ox);
                    UH t; t.u = fyfx[it];
                    h16 fy = t.h[0], fx = t.h[1];
                    h16x8 r0 = v00.h + (v10.h - v00.h) * fy;
                    h16x8 r1 = v01.h + (v11.h - v01.h) * fy;
                    F8 rr; rr.h = r0 + (r1 - r0) * fx;
                    lo8 = make_uint2(rr.u.x, rr.u.y);
                    hi8 = make_uint2(rr.u.z, rr.u.w);
                }
                *(uint2*)&buf[lo] = lo8;
                *(uint2*)&buf[lo + 4] = hi8;
            }
        } else if (UPS) {
            int cs = c0 - C1n;
#pragma unroll
            for (int it = 0; it < MAXIT; ++it) {
                int lo = lof[it];
                if (lo < 0) continue;
                uint4 v = {0u, 0u, 0u, 0u};
                int g = g2[it];
                if (g >= 0) v = *(const uint4*)(src2 + g + cs);
                *(uint2*)&buf[lo] = make_uint2(v.x, v.y);
                *(uint2*)&buf[lo + 4] = make_uint2(v.z, v.w);
            }
        } else {
#pragma unroll
            for (int it = 0; it < MAXIT; ++it) {
                int lo = lof[it];
                if (lo < 0) continue;
                uint4 v = {0u, 0u, 0u, 0u};
                int g = g1[it];
                if (g >= 0) v = *(const uint4*)(src1 + g + c0);
                *(uint2*)&buf[lo] = make_uint2(v.x, v.y);
                *(uint2*)&buf[lo + 4] = make_uint2(v.z, v.w);
            }
        }
    };

    // ---- row-cached MFMA sweep + A-group double-buffering ----------------
    // areg[cur] feeds MFMAs for group kx while areg[cur^1] is being loaded
    // for kx+1 -> compiler emits partial vmcnt waits, hiding A-load latency.
    const uint4* PW4 = (const uint4*)PW;
    auto sweep = [&](int ci, const unsigned short* buf) {
        size_t abase = (((size_t)cb * TAPS) * nch + ci) * (MT * 64) + lane;
        const size_t astep = (size_t)nch * (MT * 64);
        F8 areg[2][KH][MT];
#pragma unroll
        for (int ky = 0; ky < KH; ++ky)
#pragma unroll
            for (int mt = 0; mt < MT; ++mt)
                areg[0][ky][mt].u = PW4[abase + (size_t)(ky * KW) * astep + mt * 64];
        int cur = 0;
#pragma unroll
        for (int kx = 0; kx < KW; ++kx) {
            if (kx + 1 < KW) {
#pragma unroll
                for (int ky = 0; ky < KH; ++ky)
#pragma unroll
                    for (int mt = 0; mt < MT; ++mt)
                        areg[cur ^ 1][ky][mt].u =
                            PW4[abase + (size_t)(ky * KW + kx + 1) * astep + mt * 64];
            }
#pragma unroll
            for (int wr = 0; wr < 2 + KH - 1; ++wr) {
#pragma unroll
                for (int cg = 0; cg < 2; ++cg) {
                    int row = (wv << 1) + wr;
                    int col = (cg << 4) + m16;
                    int li = (row * WINW + col + kx) * 36 + quad * 8;
                    F8 bf;
                    ((uint2*)&bf)[0] = *(const uint2*)&buf[li];
                    ((uint2*)&bf)[1] = *(const uint2*)&buf[li + 4];
#pragma unroll
                    for (int ky = 0; ky < KH; ++ky) {
                        int ntr = wr - ky;
                        if (ntr < 0 || ntr > 1) continue;
                        int nt = (ntr << 1) + cg;
#pragma unroll
                        for (int mt = 0; mt < MT; ++mt)
                            acc[mt][nt] = __builtin_amdgcn_mfma_f32_16x16x32_f16(
                                areg[cur][ky][mt].h, bf.h, acc[mt][nt], 0, 0, 0);
                    }
                }
            }
            cur ^= 1;
        }
    };

    // ---- double-buffered K-loop: one barrier per chunk ----
    stage(0, lds[0]);
    __syncthreads();
    for (int ci = 0; ci < nch; ++ci) {
        int p = ci & 1;
        if (ci + 1 < nch) stage((ci + 1) << 5, lds[p ^ 1]);
        sweep(ci, lds[p]);
        __syncthreads();
    }

    // ---- epilogue: bias + PReLU, NHWC store ----
    const float alpha = pa[aidx];
#pragma unroll
    for (int mt = 0; mt < MT; ++mt) {
        int co = co_base + mt * 16 + quad * 4;
        float4 bi = *(const float4*)(bias + co);
#pragma unroll
        for (int nt = 0; nt < 4; ++nt) {
            int y = y0 + (wv << 1) + (nt >> 1);
            int x = x0 + ((nt & 1) << 4) + m16;
            float v0 = acc[mt][nt][0] + bi.x;
            float v1 = acc[mt][nt][1] + bi.y;
            float v2 = acc[mt][nt][2] + bi.z;
            float v3 = acc[mt][nt][3] + bi.w;
            v0 = v0 >= 0.f ? v0 : alpha * v0;
            v1 = v1 >= 0.f ? v1 : alpha * v1;
            v2 = v2 >= 0.f ? v2 : alpha * v2;
            v3 = v3 >= 0.f ? v3 : alpha * v3;
            uint2 r; r.x = pack2(v0, v1); r.y = pack2(v2, v3);
            *(uint2*)(out + ((size_t)((b * Ho + y) * Wo + x)) * Cout + co) = r;
        }
    }
}

// ---- dynamic per-sample conv 8x8 pad3 + PReLU[0], NHWC out ----------------
__global__ __launch_bounds__(256) void k_dynconv(
    const float* __restrict__ x,   // [8,256,256] fp32
    const float* __restrict__ w,   // [8,32,8,8] fp32
    const float* __restrict__ pa,
    h16* __restrict__ out)         // [8,255,255,32] NHWC
{
    __shared__ float wl[2048];     // [tap][co]
    int b = blockIdx.y;
    for (int j = threadIdx.x; j < 2048; j += 256) {
        int t = j >> 5, co = j & 31;
        wl[j] = w[((size_t)(b * 32 + co)) * 64 + t];
    }
    __syncthreads();
    int idx = blockIdx.x * 256 + threadIdx.x;
    if (idx >= 65025) return;
    int py = idx / 255, px = idx - py * 255;
    float acc[32];
#pragma unroll
    for (int c = 0; c < 32; ++c) acc[c] = 0.f;
    const float* xp = x + (size_t)b * 65536;
#pragma unroll
    for (int ky = 0; ky < 8; ++ky) {
        int iy = py + ky - 3;
        if ((unsigned)iy >= 256u) continue;
        const float* row = xp + iy * 256;
#pragma unroll
        for (int kx = 0; kx < 8; ++kx) {
            int ix = px + kx - 3;
            if ((unsigned)ix >= 256u) continue;
            float v = row[ix];
            const float4* wr = (const float4*)&wl[(ky * 8 + kx) * 32];
#pragma unroll
            for (int cg = 0; cg < 8; ++cg) {
                float4 wv = wr[cg];
                acc[cg*4+0] += v * wv.x; acc[cg*4+1] += v * wv.y;
                acc[cg*4+2] += v * wv.z; acc[cg*4+3] += v * wv.w;
            }
        }
    }
    float a = pa[0];
    h16* op = out + ((size_t)(b * 65025 + idx)) * 32;
#pragma unroll
    for (int cg = 0; cg < 4; ++cg) {
        float v[8];
#pragma unroll
        for (int k = 0; k < 8; ++k) {
            float t = acc[cg * 8 + k];
            v[k] = t >= 0.f ? t : a * t;
        }
        uint4 r;
        r.x = pack2(v[0], v[1]); r.y = pack2(v[2], v[3]);
        r.z = pack2(v[4], v[5]); r.w = pack2(v[6], v[7]);
        *(uint4*)(op + cg * 8) = r;
    }
}

// ---- maxpool 2x2, NHWC, vector 8ch ----------------------------------------
__global__ __launch_bounds__(256) void k_pool(
    const h16* __restrict__ in, h16* __restrict__ out,
    int Hin, int Win, int C, int lc8, int lwo, int count)
{
    int idx = blockIdx.x * 256 + threadIdx.x;
    if (idx >= count) return;
    int b = blockIdx.y;
    int c8 = idx & ((1 << lc8) - 1);
    int t  = idx >> lc8;
    int ox = t & ((1 << lwo) - 1);
    int oy = t >> lwo;
    const h16* p = in + ((size_t)((b * Hin + oy * 2) * Win + ox * 2)) * C + c8 * 8;
    uint4 v00 = *(const uint4*)p;
    uint4 v01 = *(const uint4*)(p + C);
    uint4 v10 = *(const uint4*)(p + (size_t)Win * C);
    uint4 v11 = *(const uint4*)(p + (size_t)Win * C + C);
    float a[8], bb[8], c[8], d[8];
    up8(v00, a); up8(v01, bb); up8(v10, c); up8(v11, d);
    uint4 r;
    float m[8];
#pragma unroll
    for (int k = 0; k < 8; ++k) m[k] = fmaxf(fmaxf(a[k], bb[k]), fmaxf(c[k], d[k]));
    r.x = pack2(m[0], m[1]); r.y = pack2(m[2], m[3]);
    r.z = pack2(m[4], m[5]); r.w = pack2(m[6], m[7]);
    int Wo = 1 << lwo;
    *(uint4*)(out + ((size_t)((b * (Hin >> 1) + oy) * Wo + ox)) * C + c8 * 8) = r;
}

// ---- BatchNorm (training stats), NHWC -------------------------------------
__global__ __launch_bounds__(256) void k_bnstats(
    const h16* __restrict__ x, int C, int N, float* __restrict__ sums)
{
    __shared__ float ls[1024];
    for (int j = threadIdx.x; j < 2 * C; j += 256) ls[j] = 0.f;
    __syncthreads();
    int start = blockIdx.x * 256 + threadIdx.x;
    int stride = gridDim.x * 256;
    int c = start & (C - 1);
    float s = 0.f, q = 0.f;
    for (int i = start; i < N; i += stride) {
        float v = h2f(((const unsigned short*)x)[i]);
        s += v; q += v * v;
    }
    atomicAdd(&ls[c], s);
    atomicAdd(&ls[C + c], q);
    __syncthreads();
    for (int j = threadIdx.x; j < 2 * C; j += 256) atomicAdd(&sums[j], ls[j]);
}

__global__ void k_bnfin(
    const float* __restrict__ sums, const float* __restrict__ g,
    const float* __restrict__ bta, int C, float invN, float* __restrict__ sc)
{
    int c = threadIdx.x;
    if (c >= C) return;
    float mean = sums[c] * invN;
    float var  = sums[C + c] * invN - mean * mean;
    float s    = g[c] / sqrtf(var + 1e-5f);
    sc[c]      = s;
    sc[C + c]  = bta[c] - mean * s;
}

__global__ __launch_bounds__(256) void k_bnapply(
    h16* __restrict__ x, int C, int N8, const float* __restrict__ sc)
{
    __shared__ float ls[1024];
    for (int j = threadIdx.x; j < 2 * C; j += 256) ls[j] = sc[j];
    __syncthreads();
    int idx = blockIdx.x * 256 + threadIdx.x;
    if (idx >= N8) return;
    int cb = (idx << 3) & (C - 1);
    h16* p = x + (size_t)idx * 8;
    uint4 v = *(const uint4*)p;
    float f[8];
    up8(v, f);
    uint4 r;
    float o[8];
#pragma unroll
    for (int k = 0; k < 8; ++k) o[k] = f[k] * ls[cb + k] + ls[C + cb + k];
    r.x = pack2(o[0], o[1]); r.y = pack2(o[2], o[3]);
    r.z = pack2(o[4], o[5]); r.w = pack2(o[6], o[7]);
    *(uint4*)p = r;
}

// ---- final 1x1 conv 32->1, fp32 out ---------------------------------------
__global__ __launch_bounds__(256) void k_final(
    const h16* __restrict__ in, const float* __restrict__ w,
    const float* __restrict__ bias, float* __restrict__ out)
{
    int idx = blockIdx.x * 256 + threadIdx.x;
    if (idx >= 524288) return;
    const h16* p = in + (size_t)idx * 32;
    float acc = bias[0];
#pragma unroll
    for (int cg = 0; cg < 4; ++cg) {
        uint4 v = *(const uint4*)(p + cg * 8);
        float f[8];
        up8(v, f);
#pragma unroll
        for (int k = 0; k < 8; ++k) acc += f[k] * w[cg * 8 + k];
    }
    out[idx] = acc;
}

extern "C" void kernel_launch(void* const* d_in, const int* in_sizes, int n_in,
                              void* d_out, int out_size, void* d_ws, size_t ws_size,
                              hipStream_t stream)
{
    const float* x      = (const float*)d_in[0];
    const float* w      = (const float*)d_in[1];
    const float* c1_w   = (const float*)d_in[2];
    const float* c1_b   = (const float*)d_in[3];
    const float* d2_w1  = (const float*)d_in[4];
    const float* d2_b1  = (const float*)d_in[5];
    const float* d2_w2  = (const float*)d_in[6];
    const float* d2_b2  = (const float*)d_in[7];
    const float* d3_w1  = (const float*)d_in[8];
    const float* d3_b1  = (const float*)d_in[9];
    const float* d3_w2  = (const float*)d_in[10];
    const float* d3_b2  = (const float*)d_in[11];
    const float* d4_w1  = (const float*)d_in[12];
    const float* d4_b1  = (const float*)d_in[13];
    const float* d4_w2  = (const float*)d_in[14];
    const float* d4_b2  = (const float*)d_in[15];
    const float* u3_w1  = (const float*)d_in[16];
    const float* u3_b1  = (const float*)d_in[17];
    const float* u3_w2  = (const float*)d_in[18];
    const float* u3_b2  = (const float*)d_in[19];
    const float* u2_w1  = (const float*)d_in[20];
    const float* u2_b1  = (const float*)d_in[21];
    const float* u2_w2  = (const float*)d_in[22];
    const float* u2_b2  = (const float*)d_in[23];
    const float* u1_w1  = (const float*)d_in[24];
    const float* u1_b1  = (const float*)d_in[25];
    const float* u1_w2  = (const float*)d_in[26];
    const float* u1_b2  = (const float*)d_in[27];
    const float* last_w = (const float*)d_in[28];
    const float* last_b = (const float*)d_in[29];
    const float* bn1_g  = (const float*)d_in[30];
    const float* bn1_b  = (const float*)d_in[31];
    const float* bn2_g  = (const float*)d_in[32];
    const float* bn2_b  = (const float*)d_in[33];
    const float* bn3_g  = (const float*)d_in[34];
    const float* bn3_b  = (const float*)d_in[35];
    const float* bn4_g  = (const float*)d_in[36];
    const float* bn4_b  = (const float*)d_in[37];
    const float* pa     = (const float*)d_in[38];
    float* out = (float*)d_out;

    // ---- fp16 arena (identical to R3-R9, proven: 166.3 MB) ----
    h16* A0 = (h16*)d_ws;
    h16* C1 = A0;                   // c1 skip  [8,256,256,32]
    h16* C2 = A0 + 16777216;        // c2 skip  [8,128,128,128]
    h16* C3 = A0 + 33554432;        // c3 skip  [8,64,64,256]
    h16* A  = A0 + 41943040;        // t0/t1/t2/t3/u3mid/u2mid/u1mid
    h16* B  = A0 + 58720256;        // p1/p2/p3/h4/u3out/u2out/u1out
    h16* PWb= A0 + 75497472;        // packed fp16 weights (swizzled)
    float* SUMS = (float*)(A0 + 83126272);
    float* SC   = SUMS + 1024;
    size_t need = (size_t)83126272 * 2 + 8192;
    if (ws_size < need) return;

    h16* pw_c1   = PWb;
    h16* pw_d2w1 = PWb + 16384;
    h16* pw_d2w2 = PWb + 53248;
    h16* pw_d3w1 = PWb + 200704;
    h16* pw_d3w2 = PWb + 495616;
    h16* pw_d4w1 = PWb + 1085440;
    h16* pw_d4w2 = PWb + 2265088;
    h16* pw_u3w1 = PWb + 4624384;
    h16* pw_u3w2 = PWb + 6393856;
    h16* pw_u2w1 = PWb + 6983680;
    h16* pw_u2w2 = PWb + 7426048;
    h16* pw_u1w1 = PWb + 7573504;
    h16* pw_u1w2 = PWb + 7619584;

    dim3 blk(256);

    // pack with swizzle; OB = 16*MT of the consuming conv kernel
    auto pack = [&](const float* src, h16* dst, int I, int T, int O, int OB) {
        k_pack<<<dim3(((I >> 3) + 63) / 64, T, O), 64, 0, stream>>>(src, dst, I, T, OB);
    };
    pack(c1_w,  pw_c1,   32, 16, 32, 32);
    pack(d2_w1, pw_d2w1, 32,  9, 128, 64);
    pack(d2_w2, pw_d2w2, 128, 9, 128, 64);
    pack(d3_w1, pw_d3w1, 128, 9, 256, 64);
    pack(d3_w2, pw_d3w2, 256, 9, 256, 64);
    pack(d4_w1, pw_d4w1, 256, 9, 512, 32);   // d4 layers consumed at MT=2
    pack(d4_w2, pw_d4w2, 512, 9, 512, 32);
    pack(u3_w1, pw_u3w1, 768, 9, 256, 64);
    pack(u3_w2, pw_u3w2, 256, 9, 256, 64);
    pack(u2_w1, pw_u2w1, 384, 9, 128, 64);
    pack(u2_w2, pw_u2w2, 128, 9, 128, 64);
    pack(u1_w1, pw_u1w1, 160, 9, 32, 32);
    pack(u1_w2, pw_u1w2, 32,  9, 32, 32);

    auto bn = [&](h16* buf, int C, int N, const float* g, const float* bb) {
        hipMemsetAsync(SUMS, 0, 2 * C * sizeof(float), stream);
        k_bnstats<<<dim3(1024), blk, 0, stream>>>(buf, C, N, SUMS);
        k_bnfin<<<dim3(1), dim3(512), 0, stream>>>(SUMS, g, bb, C, (float)C / (float)N, SC);
        k_bnapply<<<dim3(N / 8 / 256), blk, 0, stream>>>(buf, C, N / 8, SC);
    };

    // ---- encoder ----
    k_dynconv<<<dim3(255, 8), blk, 0, stream>>>(x, w, pa, A);   // t0 -> A
    k_conv_mfma<4,4,2,false,2><<<dim3(8, 32, 8), blk, 0, stream>>>(
        A, 32, 255, 255, nullptr, 0, 255, 255, 256, 256,
        pw_c1, c1_b, pa, 1, C1, 32);
    bn(C1, 32, 16777216, bn1_g, bn1_b);
    k_pool<<<dim3(256, 8), blk, 0, stream>>>(C1, B, 256, 256, 32, 2, 7, 65536);   // p1

    k_conv_mfma<3,3,1,false,4><<<dim3(4, 16, 16), blk, 0, stream>>>(
        B, 32, 128, 128, nullptr, 0, 128, 128, 128, 128,
        pw_d2w1, d2_b1, pa, 2, A, 128);                                            // t1
    k_conv_mfma<3,3,1,false,4><<<dim3(4, 16, 16), blk, 0, stream>>>(
        A, 128, 128, 128, nullptr, 0, 128, 128, 128, 128,
        pw_d2w2, d2_b2, pa, 3, C2, 128);
    bn(C2, 128, 16777216, bn2_g, bn2_b);
    k_pool<<<dim3(256, 8), blk, 0, stream>>>(C2, B, 128, 128, 128, 4, 6, 65536);  // p2

    k_conv_mfma<3,3,1,false,4><<<dim3(2, 8, 32), blk, 0, stream>>>(
        B, 128, 64, 64, nullptr, 0, 64, 64, 64, 64,
        pw_d3w1, d3_b1, pa, 4, A, 256);                                            // t2
    k_conv_mfma<3,3,1,false,4><<<dim3(2, 8, 32), blk, 0, stream>>>(
        A, 256, 64, 64, nullptr, 0, 64, 64, 64, 64,
        pw_d3w2, d3_b2, pa, 5, C3, 256);
    bn(C3, 256, 8388608, bn3_g, bn3_b);
    k_pool<<<dim3(128, 8), blk, 0, stream>>>(C3, B, 64, 64, 256, 5, 5, 32768);    // p3

    // d4 at MT=2: grid 512 blocks -> 2 blocks/CU (was 1 at MT=4)
    k_conv_mfma<3,3,1,false,2><<<dim3(1, 4, 128), blk, 0, stream>>>(
        B, 256, 32, 32, nullptr, 0, 32, 32, 32, 32,
        pw_d4w1, d4_b1, pa, 6, A, 512);                                            // t3
    k_conv_mfma<3,3,1,false,2><<<dim3(1, 4, 128), blk, 0, stream>>>(
        A, 512, 32, 32, nullptr, 0, 32, 32, 32, 32,
        pw_d4w2, d4_b2, pa, 7, B, 512);                                            // h4
    bn(B, 512, 4194304, bn4_g, bn4_b);

    // ---- decoder (bilinear up2 fused into staging) ----
    k_conv_mfma<3,3,1,true,4><<<dim3(2, 8, 32), blk, 0, stream>>>(
        B, 512, 32, 32, C3, 256, 64, 64, 64, 64,
        pw_u3w1, u3_b1, pa, 8, A, 256);                                            // u3mid
    k_conv_mfma<3,3,1,false,4><<<dim3(2, 8, 32), blk, 0, stream>>>(
        A, 256, 64, 64, nullptr, 0, 64, 64, 64, 64,
        pw_u3w2, u3_b2, pa, 9, B, 256);                                            // u3out

    k_conv_mfma<3,3,1,true,4><<<dim3(4, 16, 16), blk, 0, stream>>>(
        B, 256, 64, 64, C2, 128, 128, 128, 128, 128,
        pw_u2w1, u2_b1, pa, 10, A, 128);                                           // u2mid
    k_conv_mfma<3,3,1,false,4><<<dim3(4, 16, 16), blk, 0, stream>>>(
        A, 128, 128, 128, nullptr, 0, 128, 128, 128, 128,
        pw_u2w2, u2_b2, pa, 11, B, 128);                                           // u2out

    k_conv_mfma<3,3,1,true,2><<<dim3(8, 32, 8), blk, 0, stream>>>(
        B, 128, 128, 128, C1, 32, 256, 256, 256, 256,
        pw_u1w1, u1_b1, pa, 12, A, 32);                                            // u1mid
    k_conv_mfma<3,3,1,false,2><<<dim3(8, 32, 8), blk, 0, stream>>>(
        A, 32, 256, 256, nullptr, 0, 256, 256, 256, 256,
        pw_u1w2, u1_b2, pa, 13, B, 32);                                            // u1out

    k_final<<<dim3(2048), blk, 0, stream>>>(B, last_w, last_b, out);
}

// Round 11
// 1185.884 us; speedup vs baseline: 1.3347x; 1.0255x over previous
//
#include <hip/hip_runtime.h>
#include <hip/hip_bf16.h>
#include <cstddef>

// ---------------------------------------------------------------------------
// UNet_config1 forward — MFMA implicit-GEMM, NHWC, fp16 storage / fp32 accum.
// R11 = R9 conv core (row-cached sweep, coalesced swizzled weights, LDS dbuf,
// launch_bounds(256,2)) + timeline fusion:
//   - 13 weight-pack launches -> 1 mega-pack
//   - bnapply+maxpool fused (levels 1-3), single memset for all BN sums
//   - final 1x1 conv fused into u1w2 epilogue (shfl-reduce over quads)
// Launches 46 -> 28. LESSONS: (256,3) spills with 64-AGPR acc (R6/R8);
// K-loop micro-pipelining is plateaued at ~34% MfmaUtil (R9/R10 neutral).
// ---------------------------------------------------------------------------

typedef _Float16 h16;
typedef __attribute__((ext_vector_type(8))) _Float16 h16x8;
typedef __attribute__((ext_vector_type(4))) float f32x4;
union F8 { uint4 u; h16x8 h; };
union UH { unsigned u; h16 h[2]; };

__device__ __forceinline__ float h2f(unsigned short s) {
    union { h16 h; unsigned short s; } c; c.s = s; return (float)c.h;
}
__device__ __forceinline__ unsigned short f2h(float f) {
    union { h16 h; unsigned short s; } c; c.h = (h16)f; return c.s;
}
__device__ __forceinline__ unsigned pack2(float a, float b) {
    return (unsigned)f2h(a) | ((unsigned)f2h(b) << 16);
}
__device__ __forceinline__ void up8(const uint4& v, float* f) {
    f[0]=h2f(v.x&0xffff); f[1]=h2f(v.x>>16);
    f[2]=h2f(v.y&0xffff); f[3]=h2f(v.y>>16);
    f[4]=h2f(v.z&0xffff); f[5]=h2f(v.z>>16);
    f[6]=h2f(v.w&0xffff); f[7]=h2f(v.w>>16);
}

// ---- mega weight pack: all 13 layers in one launch ------------------------
// swizzled dst group: (((ob*T + t)*nch + chunk)*(OB/16) + mt)*64 + lane.
struct PackDesc { const float* src; h16* dst; int I, T, OB, nGrp; };
struct PackArgs { PackDesc d[13]; int total; };

__global__ __launch_bounds__(256) void k_packall(PackArgs a)
{
    int gid = blockIdx.x * 256 + threadIdx.x;
    if (gid >= a.total) return;
    int li = 0, rel = gid;
    while (rel >= a.d[li].nGrp) { rel -= a.d[li].nGrp; ++li; }
    const PackDesc& D = a.d[li];
    int I8 = D.I >> 3;
    int o  = rel / (D.T * I8);
    int r2 = rel - o * (D.T * I8);
    int t  = r2 / I8;
    int i8 = r2 - t * I8;
    int ob = o / D.OB, om = o - ob * D.OB;
    int mt = om >> 4, m16 = om & 15;
    int chunk = i8 >> 2, quad = i8 & 3;
    int lane = quad * 16 + m16;
    int nch = D.I >> 5;
    size_t grp = ((((size_t)ob * D.T + t) * nch + chunk) * (D.OB >> 4) + mt) * 64 + lane;
    const float* src = D.src + ((size_t)o * D.I + i8 * 8) * D.T + t;
    h16* d = D.dst + grp * 8;
#pragma unroll
    for (int j = 0; j < 8; ++j) d[j] = (h16)src[(size_t)j * D.T];
}

// ---- implicit-GEMM conv: (16*MT) Cout x 256 px tile, 4 waves --------------
// FIN: fuse trailing 1x1 conv (Cout->1, fp32 out) into the epilogue.
template<int KH, int KW, int PAD, bool UPS, int MT, bool FIN>
__global__ __launch_bounds__(256, 2) void k_conv_mfma(
    const h16* __restrict__ src1, int C1n, int H1, int W1,
    const h16* __restrict__ src2, int C2n,
    int Hin, int Win, int Ho, int Wo,
    const h16* __restrict__ PW, const float* __restrict__ bias,
    const float* __restrict__ pa, int aidx,
    h16* __restrict__ out, int Cout,
    const float* __restrict__ fw, const float* __restrict__ fb,
    float* __restrict__ fout)
{
    constexpr int WINH = 8 + KH - 1, WINW = 32 + KW - 1;
    constexpr int NPIX = WINH * WINW;
    constexpr int NIT  = NPIX * 4;
    constexpr int MAXIT = (NIT + 255) / 256;
    constexpr int TAPS = KH * KW;
    __shared__ unsigned short lds[2][NPIX * 36];

    const int tid = threadIdx.x;
    const int lane = tid & 63, wv = tid >> 6;
    const int quad = lane >> 4, m16 = lane & 15;
    const int nCb = Cout / (16 * MT);
    const int b  = blockIdx.z / nCb, cb = blockIdx.z % nCb;
    const int x0 = blockIdx.x * 32, y0 = blockIdx.y * 8;
    const int Cin = C1n + C2n;
    const int nch = Cin >> 5;
    const int co_base = cb * (16 * MT);
    const int srcH = UPS ? Hin : H1;
    const int srcW = UPS ? Win : W1;

    // ---- chunk-invariant staging precompute (registers) ----
    int lof[MAXIT];
    int g1[MAXIT];
    int fl[MAXIT];
    unsigned fyfx[MAXIT];
    int g2[MAXIT];

    const float ry = UPS ? (float)(H1 - 1) / (float)(Hin - 1) : 0.f;
    const float rx = UPS ? (float)(W1 - 1) / (float)(Win - 1) : 0.f;
    const int W1C = UPS ? W1 * C1n : 0;

#pragma unroll
    for (int it = 0; it < MAXIT; ++it) {
        int i = tid + it * 256;
        if (i >= NIT) { lof[it] = -1; g1[it] = -1; g2[it] = -1; fl[it] = 0; fyfx[it] = 0; continue; }
        int p = i >> 2, q = i & 3;
        int wy = p / WINW, wx = p - wy * WINW;
        int yy = y0 - PAD + wy, xx = x0 - PAD + wx;
        lof[it] = p * 36 + q * 8;
        bool val = (unsigned)yy < (unsigned)srcH && (unsigned)xx < (unsigned)srcW;
        if (UPS) {
            fl[it] = 0; fyfx[it] = 0; g1[it] = -1; g2[it] = -1;
            if (val) {
                float ys = yy * ry, xs = xx * rx;
                int yl0 = (int)ys, xl0 = (int)xs;
                float fy = ys - (float)yl0, fx = xs - (float)xl0;
                g1[it] = ((b * H1 + yl0) * W1 + xl0) * C1n + q * 8;
                fl[it] = (yl0 < H1 - 1 ? 1 : 0) | (xl0 < W1 - 1 ? 2 : 0);
                fyfx[it] = pack2(fy, fx);
                g2[it] = ((b * Hin + yy) * Win + xx) * C2n + q * 8;
            }
        } else {
            fl[it] = 0; fyfx[it] = 0; g2[it] = -1;
            g1[it] = val ? ((b * H1 + yy) * W1 + xx) * C1n + q * 8 : -1;
        }
    }

    // ---- accumulators ----
    f32x4 acc[MT][4];
#pragma unroll
    for (int i = 0; i < MT; ++i)
#pragma unroll
        for (int j = 0; j < 4; ++j) acc[i][j] = (f32x4){0.f, 0.f, 0.f, 0.f};

    // ---- staging into a given LDS buffer ----
    auto stage = [&](int c0, unsigned short* buf) {
        if (UPS && c0 < C1n) {
#pragma unroll
            for (int it = 0; it < MAXIT; ++it) {
                int lo = lof[it];
                if (lo < 0) continue;
                uint2 lo8 = {0u, 0u}, hi8 = {0u, 0u};
                int g = g1[it];
                if (g >= 0) {
                    const h16* p00 = src1 + g + c0;
                    int oy = (fl[it] & 1) ? W1C : 0;
                    int ox = (fl[it] & 2) ? C1n : 0;
                    F8 v00, v01, v10, v11;
                    v00.u = *(const uint4*)(p00);
                    v01.u = *(const uint4*)(p00 + ox);
                    v10.u = *(const uint4*)(p00 + oy);
                    v11.u = *(const uint4*)(p00 + oy + ox);
                    UH t; t.u = fyfx[it];
                    h16 fy = t.h[0], fx = t.h[1];
                    h16x8 r0 = v00.h + (v10.h - v00.h) * fy;
                    h16x8 r1 = v01.h + (v11.h - v01.h) * fy;
                    F8 rr; rr.h = r0 + (r1 - r0) * fx;
                    lo8 = make_uint2(rr.u.x, rr.u.y);
                    hi8 = make_uint2(rr.u.z, rr.u.w);
                }
                *(uint2*)&buf[lo] = lo8;
                *(uint2*)&buf[lo + 4] = hi8;
            }
        } else if (UPS) {
            int cs = c0 - C1n;
#pragma unroll
            for (int it = 0; it < MAXIT; ++it) {
                int lo = lof[it];
                if (lo < 0) continue;
                uint4 v = {0u, 0u, 0u, 0u};
                int g = g2[it];
                if (g >= 0) v = *(const uint4*)(src2 + g + cs);
                *(uint2*)&buf[lo] = make_uint2(v.x, v.y);
                *(uint2*)&buf[lo + 4] = make_uint2(v.z, v.w);
            }
        } else {
#pragma unroll
            for (int it = 0; it < MAXIT; ++it) {
                int lo = lof[it];
                if (lo < 0) continue;
                uint4 v = {0u, 0u, 0u, 0u};
                int g = g1[it];
                if (g >= 0) v = *(const uint4*)(src1 + g + c0);
                *(uint2*)&buf[lo] = make_uint2(v.x, v.y);
                *(uint2*)&buf[lo + 4] = make_uint2(v.z, v.w);
            }
        }
    };

    // ---- row-cached MFMA sweep (R9): each distinct B-fragment read once ---
    const uint4* PW4 = (const uint4*)PW;
    auto sweep = [&](int ci, const unsigned short* buf) {
        size_t abase = (((size_t)cb * TAPS) * nch + ci) * (MT * 64) + lane;
        const size_t astep = (size_t)nch * (MT * 64);
#pragma unroll
        for (int kx = 0; kx < KW; ++kx) {
            F8 a[KH][MT];
#pragma unroll
            for (int ky = 0; ky < KH; ++ky)
#pragma unroll
                for (int mt = 0; mt < MT; ++mt)
                    a[ky][mt].u = PW4[abase + (size_t)(ky * KW + kx) * astep + mt * 64];
#pragma unroll
            for (int wr = 0; wr < 2 + KH - 1; ++wr) {
#pragma unroll
                for (int cg = 0; cg < 2; ++cg) {
                    int row = (wv << 1) + wr;
                    int col = (cg << 4) + m16;
                    int li = (row * WINW + col + kx) * 36 + quad * 8;
                    F8 bf;
                    ((uint2*)&bf)[0] = *(const uint2*)&buf[li];
                    ((uint2*)&bf)[1] = *(const uint2*)&buf[li + 4];
#pragma unroll
                    for (int ky = 0; ky < KH; ++ky) {
                        int ntr = wr - ky;
                        if (ntr < 0 || ntr > 1) continue;
                        int nt = (ntr << 1) + cg;
#pragma unroll
                        for (int mt = 0; mt < MT; ++mt)
                            acc[mt][nt] = __builtin_amdgcn_mfma_f32_16x16x32_f16(
                                a[ky][mt].h, bf.h, acc[mt][nt], 0, 0, 0);
                    }
                }
            }
        }
    };

    // ---- double-buffered K-loop: one barrier per chunk ----
    stage(0, lds[0]);
    __syncthreads();
    for (int ci = 0; ci < nch; ++ci) {
        int p = ci & 1;
        if (ci + 1 < nch) stage((ci + 1) << 5, lds[p ^ 1]);
        sweep(ci, lds[p]);
        __syncthreads();
    }

    // ---- epilogue: bias + PReLU; store NHWC, or fused 1x1 -> fp32 out ----
    const float alpha = pa[aidx];
    float fin_acc[4] = {0.f, 0.f, 0.f, 0.f};
#pragma unroll
    for (int mt = 0; mt < MT; ++mt) {
        int co = co_base + mt * 16 + quad * 4;
        float4 bi = *(const float4*)(bias + co);
        float4 fw4 = {0.f, 0.f, 0.f, 0.f};
        if (FIN) fw4 = *(const float4*)(fw + co);
#pragma unroll
        for (int nt = 0; nt < 4; ++nt) {
            int y = y0 + (wv << 1) + (nt >> 1);
            int x = x0 + ((nt & 1) << 4) + m16;
            float v0 = acc[mt][nt][0] + bi.x;
            float v1 = acc[mt][nt][1] + bi.y;
            float v2 = acc[mt][nt][2] + bi.z;
            float v3 = acc[mt][nt][3] + bi.w;
            v0 = v0 >= 0.f ? v0 : alpha * v0;
            v1 = v1 >= 0.f ? v1 : alpha * v1;
            v2 = v2 >= 0.f ? v2 : alpha * v2;
            v3 = v3 >= 0.f ? v3 : alpha * v3;
            if (FIN) {
                fin_acc[nt] += v0 * fw4.x + v1 * fw4.y + v2 * fw4.z + v3 * fw4.w;
            } else {
                uint2 r; r.x = pack2(v0, v1); r.y = pack2(v2, v3);
                *(uint2*)(out + ((size_t)((b * Ho + y) * Wo + x)) * Cout + co) = r;
            }
        }
    }
    if (FIN) {
        float fb0 = fb[0];
#pragma unroll
        for (int nt = 0; nt < 4; ++nt) {
            float p = fin_acc[nt];
            p += __shfl_xor(p, 16);
            p += __shfl_xor(p, 32);
            if (quad == 0) {
                int y = y0 + (wv << 1) + (nt >> 1);
                int x = x0 + ((nt & 1) << 4) + m16;
                fout[(size_t)(b * Ho + y) * Wo + x] = p + fb0;
            }
        }
    }
}

// ---- dynamic per-sample conv 8x8 pad3 + PReLU[0], NHWC out ----------------
__global__ __launch_bounds__(256) void k_dynconv(
    const float* __restrict__ x,   // [8,256,256] fp32
    const float* __restrict__ w,   // [8,32,8,8] fp32
    const float* __restrict__ pa,
    h16* __restrict__ out)         // [8,255,255,32] NHWC
{
    __shared__ float wl[2048];     // [tap][co]
    int b = blockIdx.y;
    for (int j = threadIdx.x; j < 2048; j += 256) {
        int t = j >> 5, co = j & 31;
        wl[j] = w[((size_t)(b * 32 + co)) * 64 + t];
    }
    __syncthreads();
    int idx = blockIdx.x * 256 + threadIdx.x;
    if (idx >= 65025) return;
    int py = idx / 255, px = idx - py * 255;
    float acc[32];
#pragma unroll
    for (int c = 0; c < 32; ++c) acc[c] = 0.f;
    const float* xp = x + (size_t)b * 65536;
#pragma unroll
    for (int ky = 0; ky < 8; ++ky) {
        int iy = py + ky - 3;
        if ((unsigned)iy >= 256u) continue;
        const float* row = xp + iy * 256;
#pragma unroll
        for (int kx = 0; kx < 8; ++kx) {
            int ix = px + kx - 3;
            if ((unsigned)ix >= 256u) continue;
            float v = row[ix];
            const float4* wr = (const float4*)&wl[(ky * 8 + kx) * 32];
#pragma unroll
            for (int cg = 0; cg < 8; ++cg) {
                float4 wv = wr[cg];
                acc[cg*4+0] += v * wv.x; acc[cg*4+1] += v * wv.y;
                acc[cg*4+2] += v * wv.z; acc[cg*4+3] += v * wv.w;
            }
        }
    }
    float a = pa[0];
    h16* op = out + ((size_t)(b * 65025 + idx)) * 32;
#pragma unroll
    for (int cg = 0; cg < 4; ++cg) {
        float v[8];
#pragma unroll
        for (int k = 0; k < 8; ++k) {
            float t = acc[cg * 8 + k];
            v[k] = t >= 0.f ? t : a * t;
        }
        uint4 r;
        r.x = pack2(v[0], v[1]); r.y = pack2(v[2], v[3]);
        r.z = pack2(v[4], v[5]); r.w = pack2(v[6], v[7]);
        *(uint4*)(op + cg * 8) = r;
    }
}

// ---- BatchNorm stats (training), NHWC -------------------------------------
__global__ __launch_bounds__(256) void k_bnstats(
    const h16* __restrict__ x, int C, int N, float* __restrict__ sums)
{
    __shared__ float ls[1024];
    for (int j = threadIdx.x; j < 2 * C; j += 256) ls[j] = 0.f;
    __syncthreads();
    int start = blockIdx.x * 256 + threadIdx.x;
    int stride = gridDim.x * 256;
    int c = start & (C - 1);
    float s = 0.f, q = 0.f;
    for (int i = start; i < N; i += stride) {
        float v = h2f(((const unsigned short*)x)[i]);
        s += v; q += v * v;
    }
    atomicAdd(&ls[c], s);
    atomicAdd(&ls[C + c], q);
    __syncthreads();
    for (int j = threadIdx.x; j < 2 * C; j += 256) atomicAdd(&sums[j], ls[j]);
}

__global__ void k_bnfin(
    const float* __restrict__ sums, const float* __restrict__ g,
    const float* __restrict__ bta, int C, float invN, float* __restrict__ sc)
{
    int c = threadIdx.x;
    if (c >= C) return;
    float mean = sums[c] * invN;
    float var  = sums[C + c] * invN - mean * mean;
    float s    = g[c] / sqrtf(var + 1e-5f);
    sc[c]      = s;
    sc[C + c]  = bta[c] - mean * s;
}

// ---- fused BN-apply (in place, for skip) + 2x2 maxpool --------------------
__global__ __launch_bounds__(256) void k_bnapply_pool(
    h16* __restrict__ x, h16* __restrict__ pooled,
    int Hin, int Win, int C, int lc8, int lwo, int count,
    const float* __restrict__ sc)
{
    int idx = blockIdx.x * 256 + threadIdx.x;
    if (idx >= count) return;
    int b = blockIdx.y;
    int c8 = idx & ((1 << lc8) - 1);
    int t  = idx >> lc8;
    int ox = t & ((1 << lwo) - 1);
    int oy = t >> lwo;
    int cb = c8 * 8;
    float s[8], sh[8];
#pragma unroll
    for (int k = 0; k < 8; ++k) { s[k] = sc[cb + k]; sh[k] = sc[C + cb + k]; }
    h16* p = x + ((size_t)((b * Hin + oy * 2) * Win + ox * 2)) * C + cb;
    size_t rs = (size_t)Win * C;
    uint4 v00 = *(const uint4*)p;
    uint4 v01 = *(const uint4*)(p + C);
    uint4 v10 = *(const uint4*)(p + rs);
    uint4 v11 = *(const uint4*)(p + rs + C);
    float a[8], bb[8], c[8], d[8], m[8];
    up8(v00, a); up8(v01, bb); up8(v10, c); up8(v11, d);
#pragma unroll
    for (int k = 0; k < 8; ++k) {
        a[k]  = a[k]  * s[k] + sh[k];
        bb[k] = bb[k] * s[k] + sh[k];
        c[k]  = c[k]  * s[k] + sh[k];
        d[k]  = d[k]  * s[k] + sh[k];
        m[k]  = fmaxf(fmaxf(a[k], bb[k]), fmaxf(c[k], d[k]));
    }
    uint4 r;
    r.x = pack2(a[0],a[1]);  r.y = pack2(a[2],a[3]);  r.z = pack2(a[4],a[5]);  r.w = pack2(a[6],a[7]);
    *(uint4*)p = r;
    r.x = pack2(bb[0],bb[1]); r.y = pack2(bb[2],bb[3]); r.z = pack2(bb[4],bb[5]); r.w = pack2(bb[6],bb[7]);
    *(uint4*)(p + C) = r;
    r.x = pack2(c[0],c[1]);  r.y = pack2(c[2],c[3]);  r.z = pack2(c[4],c[5]);  r.w = pack2(c[6],c[7]);
    *(uint4*)(p + rs) = r;
    r.x = pack2(d[0],d[1]);  r.y = pack2(d[2],d[3]);  r.z = pack2(d[4],d[5]);  r.w = pack2(d[6],d[7]);
    *(uint4*)(p + rs + C) = r;
    r.x = pack2(m[0],m[1]);  r.y = pack2(m[2],m[3]);  r.z = pack2(m[4],m[5]);  r.w = pack2(m[6],m[7]);
    int Wo = 1 << lwo;
    *(uint4*)(pooled + ((size_t)((b * (Hin >> 1) + oy)) * Wo + ox) * C + cb) = r;
}

// ---- plain BN apply (bn4, no pool) ----------------------------------------
__global__ __launch_bounds__(256) void k_bnapply(
    h16* __restrict__ x, int C, int N8, const float* __restrict__ sc)
{
    __shared__ float ls[1024];
    for (int j = threadIdx.x; j < 2 * C; j += 256) ls[j] = sc[j];
    __syncthreads();
    int idx = blockIdx.x * 256 + threadIdx.x;
    if (idx >= N8) return;
    int cb = (idx << 3) & (C - 1);
    h16* p = x + (size_t)idx * 8;
    uint4 v = *(const uint4*)p;
    float f[8];
    up8(v, f);
    uint4 r;
    float o[8];
#pragma unroll
    for (int k = 0; k < 8; ++k) o[k] = f[k] * ls[cb + k] + ls[C + cb + k];
    r.x = pack2(o[0], o[1]); r.y = pack2(o[2], o[3]);
    r.z = pack2(o[4], o[5]); r.w = pack2(o[6], o[7]);
    *(uint4*)p = r;
}

extern "C" void kernel_launch(void* const* d_in, const int* in_sizes, int n_in,
                              void* d_out, int out_size, void* d_ws, size_t ws_size,
                              hipStream_t stream)
{
    const float* x      = (const float*)d_in[0];
    const float* w      = (const float*)d_in[1];
    const float* c1_w   = (const float*)d_in[2];
    const float* c1_b   = (const float*)d_in[3];
    const float* d2_w1  = (const float*)d_in[4];
    const float* d2_b1  = (const float*)d_in[5];
    const float* d2_w2  = (const float*)d_in[6];
    const float* d2_b2  = (const float*)d_in[7];
    const float* d3_w1  = (const float*)d_in[8];
    const float* d3_b1  = (const float*)d_in[9];
    const float* d3_w2  = (const float*)d_in[10];
    const float* d3_b2  = (const float*)d_in[11];
    const float* d4_w1  = (const float*)d_in[12];
    const float* d4_b1  = (const float*)d_in[13];
    const float* d4_w2  = (const float*)d_in[14];
    const float* d4_b2  = (const float*)d_in[15];
    const float* u3_w1  = (const float*)d_in[16];
    const float* u3_b1  = (const float*)d_in[17];
    const float* u3_w2  = (const float*)d_in[18];
    const float* u3_b2  = (const float*)d_in[19];
    const float* u2_w1  = (const float*)d_in[20];
    const float* u2_b1  = (const float*)d_in[21];
    const float* u2_w2  = (const float*)d_in[22];
    const float* u2_b2  = (const float*)d_in[23];
    const float* u1_w1  = (const float*)d_in[24];
    const float* u1_b1  = (const float*)d_in[25];
    const float* u1_w2  = (const float*)d_in[26];
    const float* u1_b2  = (const float*)d_in[27];
    const float* last_w = (const float*)d_in[28];
    const float* last_b = (const float*)d_in[29];
    const float* bn1_g  = (const float*)d_in[30];
    const float* bn1_b  = (const float*)d_in[31];
    const float* bn2_g  = (const float*)d_in[32];
    const float* bn2_b  = (const float*)d_in[33];
    const float* bn3_g  = (const float*)d_in[34];
    const float* bn3_b  = (const float*)d_in[35];
    const float* bn4_g  = (const float*)d_in[36];
    const float* bn4_b  = (const float*)d_in[37];
    const float* pa     = (const float*)d_in[38];
    float* out = (float*)d_out;

    // ---- fp16 arena (identical layout; SUMS grown to 2048 floats) ----
    h16* A0 = (h16*)d_ws;
    h16* C1 = A0;                   // c1 skip  [8,256,256,32]
    h16* C2 = A0 + 16777216;        // c2 skip  [8,128,128,128]
    h16* C3 = A0 + 33554432;        // c3 skip  [8,64,64,256]
    h16* A  = A0 + 41943040;        // t0/t1/t2/t3/u3mid/u2mid/u1mid
    h16* B  = A0 + 58720256;        // p1/p2/p3/h4/u3out/u2out/u1out
    h16* PWb= A0 + 75497472;        // packed fp16 weights (swizzled)
    float* SUMS = (float*)(A0 + 83126272);   // 2048 floats (4 BN regions)
    float* SC   = SUMS + 2048;               // 1024 floats
    size_t need = (size_t)83126272 * 2 + 3072 * 4;
    if (ws_size < need) return;

    h16* pw_c1   = PWb;
    h16* pw_d2w1 = PWb + 16384;
    h16* pw_d2w2 = PWb + 53248;
    h16* pw_d3w1 = PWb + 200704;
    h16* pw_d3w2 = PWb + 495616;
    h16* pw_d4w1 = PWb + 1085440;
    h16* pw_d4w2 = PWb + 2265088;
    h16* pw_u3w1 = PWb + 4624384;
    h16* pw_u3w2 = PWb + 6393856;
    h16* pw_u2w1 = PWb + 6983680;
    h16* pw_u2w2 = PWb + 7426048;
    h16* pw_u1w1 = PWb + 7573504;
    h16* pw_u1w2 = PWb + 7619584;

    dim3 blk(256);

    // one memset covers all 4 BN sum regions
    hipMemsetAsync(SUMS, 0, 2048 * sizeof(float), stream);

    // ---- mega-pack (13 layers, 1 launch). OB = 16*MT of consumer. ----
    PackArgs pk;
    auto mk = [](const float* s, h16* d, int I, int T, int O, int OB) {
        return PackDesc{s, d, I, T, OB, (I >> 3) * T * O};
    };
    pk.d[0]  = mk(c1_w,  pw_c1,   32, 16, 32, 32);
    pk.d[1]  = mk(d2_w1, pw_d2w1, 32,  9, 128, 64);
    pk.d[2]  = mk(d2_w2, pw_d2w2, 128, 9, 128, 64);
    pk.d[3]  = mk(d3_w1, pw_d3w1, 128, 9, 256, 64);
    pk.d[4]  = mk(d3_w2, pw_d3w2, 256, 9, 256, 64);
    pk.d[5]  = mk(d4_w1, pw_d4w1, 256, 9, 512, 32);  // d4 consumed at MT=2
    pk.d[6]  = mk(d4_w2, pw_d4w2, 512, 9, 512, 32);
    pk.d[7]  = mk(u3_w1, pw_u3w1, 768, 9, 256, 64);
    pk.d[8]  = mk(u3_w2, pw_u3w2, 256, 9, 256, 64);
    pk.d[9]  = mk(u2_w1, pw_u2w1, 384, 9, 128, 64);
    pk.d[10] = mk(u2_w2, pw_u2w2, 128, 9, 128, 64);
    pk.d[11] = mk(u1_w1, pw_u1w1, 160, 9, 32, 32);
    pk.d[12] = mk(u1_w2, pw_u1w2, 32,  9, 32, 32);
    pk.total = 0;
    for (int i = 0; i < 13; ++i) pk.total += pk.d[i].nGrp;
    k_packall<<<dim3((pk.total + 255) / 256), blk, 0, stream>>>(pk);

    const float* NF = nullptr;
    float* NFO = nullptr;

    // ---- encoder ----
    k_dynconv<<<dim3(255, 8), blk, 0, stream>>>(x, w, pa, A);   // t0 -> A
    k_conv_mfma<4,4,2,false,2,false><<<dim3(8, 32, 8), blk, 0, stream>>>(
        A, 32, 255, 255, nullptr, 0, 255, 255, 256, 256,
        pw_c1, c1_b, pa, 1, C1, 32, NF, NF, NFO);
    // bn1 + pool -> B (p1)
    k_bnstats<<<dim3(1024), blk, 0, stream>>>(C1, 32, 16777216, SUMS);
    k_bnfin<<<dim3(1), dim3(512), 0, stream>>>(SUMS, bn1_g, bn1_b, 32, 32.f / 16777216.f, SC);
    k_bnapply_pool<<<dim3(256, 8), blk, 0, stream>>>(C1, B, 256, 256, 32, 2, 7, 65536, SC);

    k_conv_mfma<3,3,1,false,4,false><<<dim3(4, 16, 16), blk, 0, stream>>>(
        B, 32, 128, 128, nullptr, 0, 128, 128, 128, 128,
        pw_d2w1, d2_b1, pa, 2, A, 128, NF, NF, NFO);                               // t1
    k_conv_mfma<3,3,1,false,4,false><<<dim3(4, 16, 16), blk, 0, stream>>>(
        A, 128, 128, 128, nullptr, 0, 128, 128, 128, 128,
        pw_d2w2, d2_b2, pa, 3, C2, 128, NF, NF, NFO);
    k_bnstats<<<dim3(1024), blk, 0, stream>>>(C2, 128, 16777216, SUMS + 64);
    k_bnfin<<<dim3(1), dim3(512), 0, stream>>>(SUMS + 64, bn2_g, bn2_b, 128, 128.f / 16777216.f, SC);
    k_bnapply_pool<<<dim3(256, 8), blk, 0, stream>>>(C2, B, 128, 128, 128, 4, 6, 65536, SC);

    k_conv_mfma<3,3,1,false,4,false><<<dim3(2, 8, 32), blk, 0, stream>>>(
        B, 128, 64, 64, nullptr, 0, 64, 64, 64, 64,
        pw_d3w1, d3_b1, pa, 4, A, 256, NF, NF, NFO);                               // t2
    k_conv_mfma<3,3,1,false,4,false><<<dim3(2, 8, 32), blk, 0, stream>>>(
        A, 256, 64, 64, nullptr, 0, 64, 64, 64, 64,
        pw_d3w2, d3_b2, pa, 5, C3, 256, NF, NF, NFO);
    k_bnstats<<<dim3(1024), blk, 0, stream>>>(C3, 256, 8388608, SUMS + 320);
    k_bnfin<<<dim3(1), dim3(512), 0, stream>>>(SUMS + 320, bn3_g, bn3_b, 256, 256.f / 8388608.f, SC);
    k_bnapply_pool<<<dim3(128, 8), blk, 0, stream>>>(C3, B, 64, 64, 256, 5, 5, 32768, SC);

    // d4 at MT=2 (2 blocks/CU)
    k_conv_mfma<3,3,1,false,2,false><<<dim3(1, 4, 128), blk, 0, stream>>>(
        B, 256, 32, 32, nullptr, 0, 32, 32, 32, 32,
        pw_d4w1, d4_b1, pa, 6, A, 512, NF, NF, NFO);                               // t3
    k_conv_mfma<3,3,1,false,2,false><<<dim3(1, 4, 128), blk, 0, stream>>>(
        A, 512, 32, 32, nullptr, 0, 32, 32, 32, 32,
        pw_d4w2, d4_b2, pa, 7, B, 512, NF, NF, NFO);                               // h4
    k_bnstats<<<dim3(1024), blk, 0, stream>>>(B, 512, 4194304, SUMS + 832);
    k_bnfin<<<dim3(1), dim3(512), 0, stream>>>(SUMS + 832, bn4_g, bn4_b, 512, 512.f / 4194304.f, SC);
    k_bnapply<<<dim3(2048), blk, 0, stream>>>(B, 512, 524288, SC);

    // ---- decoder (bilinear up2 fused into staging) ----
    k_conv_mfma<3,3,1,true,4,false><<<dim3(2, 8, 32), blk, 0, stream>>>(
        B, 512, 32, 32, C3, 256, 64, 64, 64, 64,
        pw_u3w1, u3_b1, pa, 8, A, 256, NF, NF, NFO);                               // u3mid
    k_conv_mfma<3,3,1,false,4,false><<<dim3(2, 8, 32), blk, 0, stream>>>(
        A, 256, 64, 64, nullptr, 0, 64, 64, 64, 64,
        pw_u3w2, u3_b2, pa, 9, B, 256, NF, NF, NFO);                               // u3out

    k_conv_mfma<3,3,1,true,4,false><<<dim3(4, 16, 16), blk, 0, stream>>>(
        B, 256, 64, 64, C2, 128, 128, 128, 128, 128,
        pw_u2w1, u2_b1, pa, 10, A, 128, NF, NF, NFO);                              // u2mid
    k_conv_mfma<3,3,1,false,4,false><<<dim3(4, 16, 16), blk, 0, stream>>>(
        A, 128, 128, 128, nullptr, 0, 128, 128, 128, 128,
        pw_u2w2, u2_b2, pa, 11, B, 128, NF, NF, NFO);                              // u2out

    k_conv_mfma<3,3,1,true,2,false><<<dim3(8, 32, 8), blk, 0, stream>>>(
        B, 128, 128, 128, C1, 32, 256, 256, 256, 256,
        pw_u1w1, u1_b1, pa, 12, A, 32, NF, NF, NFO);                               // u1mid
    // u1w2 with fused final 1x1 -> fp32 d_out (u1out never materialized)
    k_conv_mfma<3,3,1,false,2,true><<<dim3(8, 32, 8), blk, 0, stream>>>(
        A, 32, 256, 256, nullptr, 0, 256, 256, 256, 256,
        pw_u1w2, u1_b2, pa, 13, B, 32, last_w, last_b, out);
}

// Round 12
// 1087.234 us; speedup vs baseline: 1.4558x; 1.0907x over previous
//
#include <hip/hip_runtime.h>
#include <hip/hip_bf16.h>
#include <cstddef>

// ---------------------------------------------------------------------------
// UNet_config1 forward — MFMA implicit-GEMM, NHWC, fp16 storage / fp32 accum.
// R12 = R11 + BN-stats fused into producing convs (BNS flag: shfl+LDS reduce
// + global atomics from the fp32 epilogue) and bnfin inlined into the apply
// kernels. Launches 24 -> 20. LESSONS: (256,3) spills with 64-AGPR acc
// (R6/R8); conv K-loop micro-pipelining plateaued at ~34% MfmaUtil (R9/R10).
// ---------------------------------------------------------------------------

typedef _Float16 h16;
typedef __attribute__((ext_vector_type(8))) _Float16 h16x8;
typedef __attribute__((ext_vector_type(4))) float f32x4;
union F8 { uint4 u; h16x8 h; };
union UH { unsigned u; h16 h[2]; };

__device__ __forceinline__ float h2f(unsigned short s) {
    union { h16 h; unsigned short s; } c; c.s = s; return (float)c.h;
}
__device__ __forceinline__ unsigned short f2h(float f) {
    union { h16 h; unsigned short s; } c; c.h = (h16)f; return c.s;
}
__device__ __forceinline__ unsigned pack2(float a, float b) {
    return (unsigned)f2h(a) | ((unsigned)f2h(b) << 16);
}
__device__ __forceinline__ void up8(const uint4& v, float* f) {
    f[0]=h2f(v.x&0xffff); f[1]=h2f(v.x>>16);
    f[2]=h2f(v.y&0xffff); f[3]=h2f(v.y>>16);
    f[4]=h2f(v.z&0xffff); f[5]=h2f(v.z>>16);
    f[6]=h2f(v.w&0xffff); f[7]=h2f(v.w>>16);
}

// ---- mega weight pack: all 13 layers in one launch ------------------------
struct PackDesc { const float* src; h16* dst; int I, T, OB, nGrp; };
struct PackArgs { PackDesc d[13]; int total; };

__global__ __launch_bounds__(256) void k_packall(PackArgs a)
{
    int gid = blockIdx.x * 256 + threadIdx.x;
    if (gid >= a.total) return;
    int li = 0, rel = gid;
    while (rel >= a.d[li].nGrp) { rel -= a.d[li].nGrp; ++li; }
    const PackDesc& D = a.d[li];
    int I8 = D.I >> 3;
    int o  = rel / (D.T * I8);
    int r2 = rel - o * (D.T * I8);
    int t  = r2 / I8;
    int i8 = r2 - t * I8;
    int ob = o / D.OB, om = o - ob * D.OB;
    int mt = om >> 4, m16 = om & 15;
    int chunk = i8 >> 2, quad = i8 & 3;
    int lane = quad * 16 + m16;
    int nch = D.I >> 5;
    size_t grp = ((((size_t)ob * D.T + t) * nch + chunk) * (D.OB >> 4) + mt) * 64 + lane;
    const float* src = D.src + ((size_t)o * D.I + i8 * 8) * D.T + t;
    h16* d = D.dst + grp * 8;
#pragma unroll
    for (int j = 0; j < 8; ++j) d[j] = (h16)src[(size_t)j * D.T];
}

// ---- implicit-GEMM conv: (16*MT) Cout x 256 px tile, 4 waves --------------
// FIN: fuse trailing 1x1 conv (Cout->1, fp32 out). BNS: accumulate BN
// sum/sumsq (fp32, pre-rounding) into gsums[Cout*2] via atomics.
template<int KH, int KW, int PAD, bool UPS, int MT, bool FIN, bool BNS>
__global__ __launch_bounds__(256, 2) void k_conv_mfma(
    const h16* __restrict__ src1, int C1n, int H1, int W1,
    const h16* __restrict__ src2, int C2n,
    int Hin, int Win, int Ho, int Wo,
    const h16* __restrict__ PW, const float* __restrict__ bias,
    const float* __restrict__ pa, int aidx,
    h16* __restrict__ out, int Cout,
    const float* __restrict__ fw, const float* __restrict__ fb,
    float* __restrict__ fout, float* __restrict__ gsums)
{
    constexpr int WINH = 8 + KH - 1, WINW = 32 + KW - 1;
    constexpr int NPIX = WINH * WINW;
    constexpr int NIT  = NPIX * 4;
    constexpr int MAXIT = (NIT + 255) / 256;
    constexpr int TAPS = KH * KW;
    __shared__ unsigned short lds[2][NPIX * 36];
    __shared__ float bnred[128];

    const int tid = threadIdx.x;
    const int lane = tid & 63, wv = tid >> 6;
    const int quad = lane >> 4, m16 = lane & 15;
    const int nCb = Cout / (16 * MT);
    const int b  = blockIdx.z / nCb, cb = blockIdx.z % nCb;
    const int x0 = blockIdx.x * 32, y0 = blockIdx.y * 8;
    const int Cin = C1n + C2n;
    const int nch = Cin >> 5;
    const int co_base = cb * (16 * MT);
    const int srcH = UPS ? Hin : H1;
    const int srcW = UPS ? Win : W1;

    // ---- chunk-invariant staging precompute (registers) ----
    int lof[MAXIT];
    int g1[MAXIT];
    int fl[MAXIT];
    unsigned fyfx[MAXIT];
    int g2[MAXIT];

    const float ry = UPS ? (float)(H1 - 1) / (float)(Hin - 1) : 0.f;
    const float rx = UPS ? (float)(W1 - 1) / (float)(Win - 1) : 0.f;
    const int W1C = UPS ? W1 * C1n : 0;

#pragma unroll
    for (int it = 0; it < MAXIT; ++it) {
        int i = tid + it * 256;
        if (i >= NIT) { lof[it] = -1; g1[it] = -1; g2[it] = -1; fl[it] = 0; fyfx[it] = 0; continue; }
        int p = i >> 2, q = i & 3;
        int wy = p / WINW, wx = p - wy * WINW;
        int yy = y0 - PAD + wy, xx = x0 - PAD + wx;
        lof[it] = p * 36 + q * 8;
        bool val = (unsigned)yy < (unsigned)srcH && (unsigned)xx < (unsigned)srcW;
        if (UPS) {
            fl[it] = 0; fyfx[it] = 0; g1[it] = -1; g2[it] = -1;
            if (val) {
                float ys = yy * ry, xs = xx * rx;
                int yl0 = (int)ys, xl0 = (int)xs;
                float fy = ys - (float)yl0, fx = xs - (float)xl0;
                g1[it] = ((b * H1 + yl0) * W1 + xl0) * C1n + q * 8;
                fl[it] = (yl0 < H1 - 1 ? 1 : 0) | (xl0 < W1 - 1 ? 2 : 0);
                fyfx[it] = pack2(fy, fx);
                g2[it] = ((b * Hin + yy) * Win + xx) * C2n + q * 8;
            }
        } else {
            fl[it] = 0; fyfx[it] = 0; g2[it] = -1;
            g1[it] = val ? ((b * H1 + yy) * W1 + xx) * C1n + q * 8 : -1;
        }
    }

    // ---- accumulators ----
    f32x4 acc[MT][4];
#pragma unroll
    for (int i = 0; i < MT; ++i)
#pragma unroll
        for (int j = 0; j < 4; ++j) acc[i][j] = (f32x4){0.f, 0.f, 0.f, 0.f};

    // ---- staging into a given LDS buffer ----
    auto stage = [&](int c0, unsigned short* buf) {
        if (UPS && c0 < C1n) {
#pragma unroll
            for (int it = 0; it < MAXIT; ++it) {
                int lo = lof[it];
                if (lo < 0) continue;
                uint2 lo8 = {0u, 0u}, hi8 = {0u, 0u};
                int g = g1[it];
                if (g >= 0) {
                    const h16* p00 = src1 + g + c0;
                    int oy = (fl[it] & 1) ? W1C : 0;
                    int ox = (fl[it] & 2) ? C1n : 0;
                    F8 v00, v01, v10, v11;
                    v00.u = *(const uint4*)(p00);
                    v01.u = *(const uint4*)(p00 + ox);
                    v10.u = *(const uint4*)(p00 + oy);
                    v11.u = *(const uint4*)(p00 + oy + ox);
                    UH t; t.u = fyfx[it];
                    h16 fy = t.h[0], fx = t.h[1];
                    h16x8 r0 = v00.h + (v10.h - v00.h) * fy;
                    h16x8 r1 = v01.h + (v11.h - v01.h) * fy;
                    F8 rr; rr.h = r0 + (r1 - r0) * fx;
                    lo8 = make_uint2(rr.u.x, rr.u.y);
                    hi8 = make_uint2(rr.u.z, rr.u.w);
                }
                *(uint2*)&buf[lo] = lo8;
                *(uint2*)&buf[lo + 4] = hi8;
            }
        } else if (UPS) {
            int cs = c0 - C1n;
#pragma unroll
            for (int it = 0; it < MAXIT; ++it) {
                int lo = lof[it];
                if (lo < 0) continue;
                uint4 v = {0u, 0u, 0u, 0u};
                int g = g2[it];
                if (g >= 0) v = *(const uint4*)(src2 + g + cs);
                *(uint2*)&buf[lo] = make_uint2(v.x, v.y);
                *(uint2*)&buf[lo + 4] = make_uint2(v.z, v.w);
            }
        } else {
#pragma unroll
            for (int it = 0; it < MAXIT; ++it) {
                int lo = lof[it];
                if (lo < 0) continue;
                uint4 v = {0u, 0u, 0u, 0u};
                int g = g1[it];
                if (g >= 0) v = *(const uint4*)(src1 + g + c0);
                *(uint2*)&buf[lo] = make_uint2(v.x, v.y);
                *(uint2*)&buf[lo + 4] = make_uint2(v.z, v.w);
            }
        }
    };

    // ---- row-cached MFMA sweep (R9): each distinct B-fragment read once ---
    const uint4* PW4 = (const uint4*)PW;
    auto sweep = [&](int ci, const unsigned short* buf) {
        size_t abase = (((size_t)cb * TAPS) * nch + ci) * (MT * 64) + lane;
        const size_t astep = (size_t)nch * (MT * 64);
#pragma unroll
        for (int kx = 0; kx < KW; ++kx) {
            F8 a[KH][MT];
#pragma unroll
            for (int ky = 0; ky < KH; ++ky)
#pragma unroll
                for (int mt = 0; mt < MT; ++mt)
                    a[ky][mt].u = PW4[abase + (size_t)(ky * KW + kx) * astep + mt * 64];
#pragma unroll
            for (int wr = 0; wr < 2 + KH - 1; ++wr) {
#pragma unroll
                for (int cg = 0; cg < 2; ++cg) {
                    int row = (wv << 1) + wr;
                    int col = (cg << 4) + m16;
                    int li = (row * WINW + col + kx) * 36 + quad * 8;
                    F8 bf;
                    ((uint2*)&bf)[0] = *(const uint2*)&buf[li];
                    ((uint2*)&bf)[1] = *(const uint2*)&buf[li + 4];
#pragma unroll
                    for (int ky = 0; ky < KH; ++ky) {
                        int ntr = wr - ky;
                        if (ntr < 0 || ntr > 1) continue;
                        int nt = (ntr << 1) + cg;
#pragma unroll
                        for (int mt = 0; mt < MT; ++mt)
                            acc[mt][nt] = __builtin_amdgcn_mfma_f32_16x16x32_f16(
                                a[ky][mt].h, bf.h, acc[mt][nt], 0, 0, 0);
                    }
                }
            }
        }
    };

    // ---- double-buffered K-loop: one barrier per chunk ----
    stage(0, lds[0]);
    if (BNS && tid < 128) bnred[tid] = 0.f;
    __syncthreads();
    for (int ci = 0; ci < nch; ++ci) {
        int p = ci & 1;
        if (ci + 1 < nch) stage((ci + 1) << 5, lds[p ^ 1]);
        sweep(ci, lds[p]);
        __syncthreads();
    }

    // ---- epilogue: bias + PReLU; store NHWC / fused 1x1 / BN stats -------
    const float alpha = pa[aidx];
    float fin_acc[4] = {0.f, 0.f, 0.f, 0.f};
    float lsum[MT][4], lsq[MT][4];
    if (BNS) {
#pragma unroll
        for (int mt = 0; mt < MT; ++mt)
#pragma unroll
            for (int j = 0; j < 4; ++j) { lsum[mt][j] = 0.f; lsq[mt][j] = 0.f; }
    }
#pragma unroll
    for (int mt = 0; mt < MT; ++mt) {
        int co = co_base + mt * 16 + quad * 4;
        float4 bi = *(const float4*)(bias + co);
        float4 fw4 = {0.f, 0.f, 0.f, 0.f};
        if (FIN) fw4 = *(const float4*)(fw + co);
#pragma unroll
        for (int nt = 0; nt < 4; ++nt) {
            int y = y0 + (wv << 1) + (nt >> 1);
            int x = x0 + ((nt & 1) << 4) + m16;
            float v0 = acc[mt][nt][0] + bi.x;
            float v1 = acc[mt][nt][1] + bi.y;
            float v2 = acc[mt][nt][2] + bi.z;
            float v3 = acc[mt][nt][3] + bi.w;
            v0 = v0 >= 0.f ? v0 : alpha * v0;
            v1 = v1 >= 0.f ? v1 : alpha * v1;
            v2 = v2 >= 0.f ? v2 : alpha * v2;
            v3 = v3 >= 0.f ? v3 : alpha * v3;
            if (BNS) {
                lsum[mt][0] += v0; lsq[mt][0] += v0 * v0;
                lsum[mt][1] += v1; lsq[mt][1] += v1 * v1;
                lsum[mt][2] += v2; lsq[mt][2] += v2 * v2;
                lsum[mt][3] += v3; lsq[mt][3] += v3 * v3;
            }
            if (FIN) {
                fin_acc[nt] += v0 * fw4.x + v1 * fw4.y + v2 * fw4.z + v3 * fw4.w;
            } else {
                uint2 r; r.x = pack2(v0, v1); r.y = pack2(v2, v3);
                *(uint2*)(out + ((size_t)((b * Ho + y) * Wo + x)) * Cout + co) = r;
            }
        }
    }
    if (FIN) {
        float fb0 = fb[0];
#pragma unroll
        for (int nt = 0; nt < 4; ++nt) {
            float p = fin_acc[nt];
            p += __shfl_xor(p, 16);
            p += __shfl_xor(p, 32);
            if (quad == 0) {
                int y = y0 + (wv << 1) + (nt >> 1);
                int x = x0 + ((nt & 1) << 4) + m16;
                fout[(size_t)(b * Ho + y) * Wo + x] = p + fb0;
            }
        }
    }
    if (BNS) {
        // reduce over the 16 m16-lanes (same channels, different pixels)
#pragma unroll
        for (int mt = 0; mt < MT; ++mt)
#pragma unroll
            for (int j = 0; j < 4; ++j) {
                float s = lsum[mt][j], q = lsq[mt][j];
                s += __shfl_xor(s, 1); q += __shfl_xor(q, 1);
                s += __shfl_xor(s, 2); q += __shfl_xor(q, 2);
                s += __shfl_xor(s, 4); q += __shfl_xor(q, 4);
                s += __shfl_xor(s, 8); q += __shfl_xor(q, 8);
                if (m16 == 0) {
                    int ch = mt * 16 + quad * 4 + j;
                    atomicAdd(&bnred[ch], s);
                    atomicAdd(&bnred[64 + ch], q);
                }
            }
        __syncthreads();
        if (tid < 16 * MT)
            atomicAdd(&gsums[co_base + tid], bnred[tid]);
        else if (tid < 32 * MT) {
            int ch = tid - 16 * MT;
            atomicAdd(&gsums[Cout + co_base + ch], bnred[64 + ch]);
        }
    }
}

// ---- dynamic per-sample conv 8x8 pad3 + PReLU[0], NHWC out ----------------
__global__ __launch_bounds__(256) void k_dynconv(
    const float* __restrict__ x,   // [8,256,256] fp32
    const float* __restrict__ w,   // [8,32,8,8] fp32
    const float* __restrict__ pa,
    h16* __restrict__ out)         // [8,255,255,32] NHWC
{
    __shared__ float wl[2048];     // [tap][co]
    int b = blockIdx.y;
    for (int j = threadIdx.x; j < 2048; j += 256) {
        int t = j >> 5, co = j & 31;
        wl[j] = w[((size_t)(b * 32 + co)) * 64 + t];
    }
    __syncthreads();
    int idx = blockIdx.x * 256 + threadIdx.x;
    if (idx >= 65025) return;
    int py = idx / 255, px = idx - py * 255;
    float acc[32];
#pragma unroll
    for (int c = 0; c < 32; ++c) acc[c] = 0.f;
    const float* xp = x + (size_t)b * 65536;
#pragma unroll
    for (int ky = 0; ky < 8; ++ky) {
        int iy = py + ky - 3;
        if ((unsigned)iy >= 256u) continue;
        const float* row = xp + iy * 256;
#pragma unroll
        for (int kx = 0; kx < 8; ++kx) {
            int ix = px + kx - 3;
            if ((unsigned)ix >= 256u) continue;
            float v = row[ix];
            const float4* wr = (const float4*)&wl[(ky * 8 + kx) * 32];
#pragma unroll
            for (int cg = 0; cg < 8; ++cg) {
                float4 wv = wr[cg];
                acc[cg*4+0] += v * wv.x; acc[cg*4+1] += v * wv.y;
                acc[cg*4+2] += v * wv.z; acc[cg*4+3] += v * wv.w;
            }
        }
    }
    float a = pa[0];
    h16* op = out + ((size_t)(b * 65025 + idx)) * 32;
#pragma unroll
    for (int cg = 0; cg < 4; ++cg) {
        float v[8];
#pragma unroll
        for (int k = 0; k < 8; ++k) {
            float t = acc[cg * 8 + k];
            v[k] = t >= 0.f ? t : a * t;
        }
        uint4 r;
        r.x = pack2(v[0], v[1]); r.y = pack2(v[2], v[3]);
        r.z = pack2(v[4], v[5]); r.w = pack2(v[6], v[7]);
        *(uint4*)(op + cg * 8) = r;
    }
}

// ---- fused BN finalize+apply (in place) + 2x2 maxpool ---------------------
__global__ __launch_bounds__(256) void k_bnapply_pool(
    h16* __restrict__ x, h16* __restrict__ pooled,
    int Hin, int Win, int C, int lc8, int lwo, int count,
    const float* __restrict__ sums, const float* __restrict__ g,
    const float* __restrict__ beta, float invN)
{
    int idx = blockIdx.x * 256 + threadIdx.x;
    if (idx >= count) return;
    int b = blockIdx.y;
    int c8 = idx & ((1 << lc8) - 1);
    int t  = idx >> lc8;
    int ox = t & ((1 << lwo) - 1);
    int oy = t >> lwo;
    int cb = c8 * 8;
    float s[8], sh[8];
#pragma unroll
    for (int k = 0; k < 8; ++k) {
        int c = cb + k;
        float mean = sums[c] * invN;
        float var  = sums[C + c] * invN - mean * mean;
        float sc   = g[c] / sqrtf(var + 1e-5f);
        s[k]  = sc;
        sh[k] = beta[c] - mean * sc;
    }
    h16* p = x + ((size_t)((b * Hin + oy * 2) * Win + ox * 2)) * C + cb;
    size_t rs = (size_t)Win * C;
    uint4 v00 = *(const uint4*)p;
    uint4 v01 = *(const uint4*)(p + C);
    uint4 v10 = *(const uint4*)(p + rs);
    uint4 v11 = *(const uint4*)(p + rs + C);
    float a[8], bb[8], c[8], d[8], m[8];
    up8(v00, a); up8(v01, bb); up8(v10, c); up8(v11, d);
#pragma unroll
    for (int k = 0; k < 8; ++k) {
        a[k]  = a[k]  * s[k] + sh[k];
        bb[k] = bb[k] * s[k] + sh[k];
        c[k]  = c[k]  * s[k] + sh[k];
        d[k]  = d[k]  * s[k] + sh[k];
        m[k]  = fmaxf(fmaxf(a[k], bb[k]), fmaxf(c[k], d[k]));
    }
    uint4 r;
    r.x = pack2(a[0],a[1]);  r.y = pack2(a[2],a[3]);  r.z = pack2(a[4],a[5]);  r.w = pack2(a[6],a[7]);
    *(uint4*)p = r;
    r.x = pack2(bb[0],bb[1]); r.y = pack2(bb[2],bb[3]); r.z = pack2(bb[4],bb[5]); r.w = pack2(bb[6],bb[7]);
    *(uint4*)(p + C) = r;
    r.x = pack2(c[0],c[1]);  r.y = pack2(c[2],c[3]);  r.z = pack2(c[4],c[5]);  r.w = pack2(c[6],c[7]);
    *(uint4*)(p + rs) = r;
    r.x = pack2(d[0],d[1]);  r.y = pack2(d[2],d[3]);  r.z = pack2(d[4],d[5]);  r.w = pack2(d[6],d[7]);
    *(uint4*)(p + rs + C) = r;
    r.x = pack2(m[0],m[1]);  r.y = pack2(m[2],m[3]);  r.z = pack2(m[4],m[5]);  r.w = pack2(m[6],m[7]);
    int Wo = 1 << lwo;
    *(uint4*)(pooled + ((size_t)((b * (Hin >> 1) + oy)) * Wo + ox) * C + cb) = r;
}

// ---- BN finalize+apply (bn4, no pool) -------------------------------------
__global__ __launch_bounds__(256) void k_bnapply(
    h16* __restrict__ x, int C, int N8,
    const float* __restrict__ sums, const float* __restrict__ g,
    const float* __restrict__ beta, float invN)
{
    int idx = blockIdx.x * 256 + threadIdx.x;
    if (idx >= N8) return;
    int cb = (idx << 3) & (C - 1);
    float s[8], sh[8];
#pragma unroll
    for (int k = 0; k < 8; ++k) {
        int c = cb + k;
        float mean = sums[c] * invN;
        float var  = sums[C + c] * invN - mean * mean;
        float sc   = g[c] / sqrtf(var + 1e-5f);
        s[k]  = sc;
        sh[k] = beta[c] - mean * sc;
    }
    h16* p = x + (size_t)idx * 8;
    uint4 v = *(const uint4*)p;
    float f[8];
    up8(v, f);
    uint4 r;
    float o[8];
#pragma unroll
    for (int k = 0; k < 8; ++k) o[k] = f[k] * s[k] + sh[k];
    r.x = pack2(o[0], o[1]); r.y = pack2(o[2], o[3]);
    r.z = pack2(o[4], o[5]); r.w = pack2(o[6], o[7]);
    *(uint4*)p = r;
}

extern "C" void kernel_launch(void* const* d_in, const int* in_sizes, int n_in,
                              void* d_out, int out_size, void* d_ws, size_t ws_size,
                              hipStream_t stream)
{
    const float* x      = (const float*)d_in[0];
    const float* w      = (const float*)d_in[1];
    const float* c1_w   = (const float*)d_in[2];
    const float* c1_b   = (const float*)d_in[3];
    const float* d2_w1  = (const float*)d_in[4];
    const float* d2_b1  = (const float*)d_in[5];
    const float* d2_w2  = (const float*)d_in[6];
    const float* d2_b2  = (const float*)d_in[7];
    const float* d3_w1  = (const float*)d_in[8];
    const float* d3_b1  = (const float*)d_in[9];
    const float* d3_w2  = (const float*)d_in[10];
    const float* d3_b2  = (const float*)d_in[11];
    const float* d4_w1  = (const float*)d_in[12];
    const float* d4_b1  = (const float*)d_in[13];
    const float* d4_w2  = (const float*)d_in[14];
    const float* d4_b2  = (const float*)d_in[15];
    const float* u3_w1  = (const float*)d_in[16];
    const float* u3_b1  = (const float*)d_in[17];
    const float* u3_w2  = (const float*)d_in[18];
    const float* u3_b2  = (const float*)d_in[19];
    const float* u2_w1  = (const float*)d_in[20];
    const float* u2_b1  = (const float*)d_in[21];
    const float* u2_w2  = (const float*)d_in[22];
    const float* u2_b2  = (const float*)d_in[23];
    const float* u1_w1  = (const float*)d_in[24];
    const float* u1_b1  = (const float*)d_in[25];
    const float* u1_w2  = (const float*)d_in[26];
    const float* u1_b2  = (const float*)d_in[27];
    const float* last_w = (const float*)d_in[28];
    const float* last_b = (const float*)d_in[29];
    const float* bn1_g  = (const float*)d_in[30];
    const float* bn1_b  = (const float*)d_in[31];
    const float* bn2_g  = (const float*)d_in[32];
    const float* bn2_b  = (const float*)d_in[33];
    const float* bn3_g  = (const float*)d_in[34];
    const float* bn3_b  = (const float*)d_in[35];
    const float* bn4_g  = (const float*)d_in[36];
    const float* bn4_b  = (const float*)d_in[37];
    const float* pa     = (const float*)d_in[38];
    float* out = (float*)d_out;

    // ---- fp16 arena (identical layout) ----
    h16* A0 = (h16*)d_ws;
    h16* C1 = A0;                   // c1 skip  [8,256,256,32]
    h16* C2 = A0 + 16777216;        // c2 skip  [8,128,128,128]
    h16* C3 = A0 + 33554432;        // c3 skip  [8,64,64,256]
    h16* A  = A0 + 41943040;        // t0/t1/t2/t3/u3mid/u2mid/u1mid
    h16* B  = A0 + 58720256;        // p1/p2/p3/h4/u3out/u2out/u1out
    h16* PWb= A0 + 75497472;        // packed fp16 weights (swizzled)
    float* SUMS = (float*)(A0 + 83126272);   // 2048 floats (4 BN regions)
    size_t need = (size_t)83126272 * 2 + 2048 * 4;
    if (ws_size < need) return;

    h16* pw_c1   = PWb;
    h16* pw_d2w1 = PWb + 16384;
    h16* pw_d2w2 = PWb + 53248;
    h16* pw_d3w1 = PWb + 200704;
    h16* pw_d3w2 = PWb + 495616;
    h16* pw_d4w1 = PWb + 1085440;
    h16* pw_d4w2 = PWb + 2265088;
    h16* pw_u3w1 = PWb + 4624384;
    h16* pw_u3w2 = PWb + 6393856;
    h16* pw_u2w1 = PWb + 6983680;
    h16* pw_u2w2 = PWb + 7426048;
    h16* pw_u1w1 = PWb + 7573504;
    h16* pw_u1w2 = PWb + 7619584;

    // BN sum regions: bn1 @0 (2*32), bn2 @64 (2*128), bn3 @320 (2*256),
    // bn4 @832 (2*512) -> 1856 total
    float* S1 = SUMS, *S2 = SUMS + 64, *S3 = SUMS + 320, *S4 = SUMS + 832;

    dim3 blk(256);
    hipMemsetAsync(SUMS, 0, 2048 * sizeof(float), stream);

    // ---- mega-pack (13 layers, 1 launch). OB = 16*MT of consumer. ----
    PackArgs pk;
    auto mk = [](const float* s, h16* d, int I, int T, int O, int OB) {
        return PackDesc{s, d, I, T, OB, (I >> 3) * T * O};
    };
    pk.d[0]  = mk(c1_w,  pw_c1,   32, 16, 32, 32);
    pk.d[1]  = mk(d2_w1, pw_d2w1, 32,  9, 128, 64);
    pk.d[2]  = mk(d2_w2, pw_d2w2, 128, 9, 128, 64);
    pk.d[3]  = mk(d3_w1, pw_d3w1, 128, 9, 256, 64);
    pk.d[4]  = mk(d3_w2, pw_d3w2, 256, 9, 256, 64);
    pk.d[5]  = mk(d4_w1, pw_d4w1, 256, 9, 512, 32);  // d4 consumed at MT=2
    pk.d[6]  = mk(d4_w2, pw_d4w2, 512, 9, 512, 32);
    pk.d[7]  = mk(u3_w1, pw_u3w1, 768, 9, 256, 64);
    pk.d[8]  = mk(u3_w2, pw_u3w2, 256, 9, 256, 64);
    pk.d[9]  = mk(u2_w1, pw_u2w1, 384, 9, 128, 64);
    pk.d[10] = mk(u2_w2, pw_u2w2, 128, 9, 128, 64);
    pk.d[11] = mk(u1_w1, pw_u1w1, 160, 9, 32, 32);
    pk.d[12] = mk(u1_w2, pw_u1w2, 32,  9, 32, 32);
    pk.total = 0;
    for (int i = 0; i < 13; ++i) pk.total += pk.d[i].nGrp;
    k_packall<<<dim3((pk.total + 255) / 256), blk, 0, stream>>>(pk);

    const float* NF = nullptr;
    float* NFO = nullptr;

    // ---- encoder ----
    k_dynconv<<<dim3(255, 8), blk, 0, stream>>>(x, w, pa, A);   // t0 -> A
    k_conv_mfma<4,4,2,false,2,false,true><<<dim3(8, 32, 8), blk, 0, stream>>>(
        A, 32, 255, 255, nullptr, 0, 255, 255, 256, 256,
        pw_c1, c1_b, pa, 1, C1, 32, NF, NF, NFO, S1);
    k_bnapply_pool<<<dim3(256, 8), blk, 0, stream>>>(
        C1, B, 256, 256, 32, 2, 7, 65536, S1, bn1_g, bn1_b, 32.f / 16777216.f);

    k_conv_mfma<3,3,1,false,4,false,false><<<dim3(4, 16, 16), blk, 0, stream>>>(
        B, 32, 128, 128, nullptr, 0, 128, 128, 128, 128,
        pw_d2w1, d2_b1, pa, 2, A, 128, NF, NF, NFO, NFO);                          // t1
    k_conv_mfma<3,3,1,false,4,false,true><<<dim3(4, 16, 16), blk, 0, stream>>>(
        A, 128, 128, 128, nullptr, 0, 128, 128, 128, 128,
        pw_d2w2, d2_b2, pa, 3, C2, 128, NF, NF, NFO, S2);
    k_bnapply_pool<<<dim3(256, 8), blk, 0, stream>>>(
        C2, B, 128, 128, 128, 4, 6, 65536, S2, bn2_g, bn2_b, 128.f / 16777216.f);

    k_conv_mfma<3,3,1,false,4,false,false><<<dim3(2, 8, 32), blk, 0, stream>>>(
        B, 128, 64, 64, nullptr, 0, 64, 64, 64, 64,
        pw_d3w1, d3_b1, pa, 4, A, 256, NF, NF, NFO, NFO);                          // t2
    k_conv_mfma<3,3,1,false,4,false,true><<<dim3(2, 8, 32), blk, 0, stream>>>(
        A, 256, 64, 64, nullptr, 0, 64, 64, 64, 64,
        pw_d3w2, d3_b2, pa, 5, C3, 256, NF, NF, NFO, S3);
    k_bnapply_pool<<<dim3(128, 8), blk, 0, stream>>>(
        C3, B, 64, 64, 256, 5, 5, 32768, S3, bn3_g, bn3_b, 256.f / 8388608.f);

    // d4 at MT=2 (2 blocks/CU)
    k_conv_mfma<3,3,1,false,2,false,false><<<dim3(1, 4, 128), blk, 0, stream>>>(
        B, 256, 32, 32, nullptr, 0, 32, 32, 32, 32,
        pw_d4w1, d4_b1, pa, 6, A, 512, NF, NF, NFO, NFO);                          // t3
    k_conv_mfma<3,3,1,false,2,false,true><<<dim3(1, 4, 128), blk, 0, stream>>>(
        A, 512, 32, 32, nullptr, 0, 32, 32, 32, 32,
        pw_d4w2, d4_b2, pa, 7, B, 512, NF, NF, NFO, S4);                           // h4
    k_bnapply<<<dim3(2048), blk, 0, stream>>>(
        B, 512, 524288, S4, bn4_g, bn4_b, 512.f / 4194304.f);

    // ---- decoder (bilinear up2 fused into staging) ----
    k_conv_mfma<3,3,1,true,4,false,false><<<dim3(2, 8, 32), blk, 0, stream>>>(
        B, 512, 32, 32, C3, 256, 64, 64, 64, 64,
        pw_u3w1, u3_b1, pa, 8, A, 256, NF, NF, NFO, NFO);                          // u3mid
    k_conv_mfma<3,3,1,false,4,false,false><<<dim3(2, 8, 32), blk, 0, stream>>>(
        A, 256, 64, 64, nullptr, 0, 64, 64, 64, 64,
        pw_u3w2, u3_b2, pa, 9, B, 256, NF, NF, NFO, NFO);                          // u3out

    k_conv_mfma<3,3,1,true,4,false,false><<<dim3(4, 16, 16), blk, 0, stream>>>(
        B, 256, 64, 64, C2, 128, 128, 128, 128, 128,
        pw_u2w1, u2_b1, pa, 10, A, 128, NF, NF, NFO, NFO);                         // u2mid
    k_conv_mfma<3,3,1,false,4,false,false><<<dim3(4, 16, 16), blk, 0, stream>>>(
        A, 128, 128, 128, nullptr, 0, 128, 128, 128, 128,
        pw_u2w2, u2_b2, pa, 11, B, 128, NF, NF, NFO, NFO);                         // u2out

    k_conv_mfma<3,3,1,true,2,false,false><<<dim3(8, 32, 8), blk, 0, stream>>>(
        B, 128, 128, 128, C1, 32, 256, 256, 256, 256,
        pw_u1w1, u1_b1, pa, 12, A, 32, NF, NF, NFO, NFO);                          // u1mid
    // u1w2 with fused final 1x1 -> fp32 d_out (u1out never materialized)
    k_conv_mfma<3,3,1,false,2,true,false><<<dim3(8, 32, 8), blk, 0, stream>>>(
        A, 32, 256, 256, nullptr, 0, 256, 256, 256, 256,
        pw_u1w2, u1_b2, pa, 13, B, 32, last_w, last_b, out, NFO);
}